// Round 4
// baseline (850.895 us; speedup 1.0000x reference)
//
#include <hip/hip_runtime.h>
#include <hip/hip_bf16.h>
#include <math.h>

typedef __hip_bfloat16 bf16;
typedef short s16x8 __attribute__((ext_vector_type(8)));
typedef short s16x4 __attribute__((ext_vector_type(4)));
typedef float f32x4 __attribute__((ext_vector_type(4)));

#define B_    4
#define N1_   2048
#define N2_   512
#define D_    768
#define H_    8
#define DK_   64
#define DV_   96
#define NPOS_ 4095
#define SCALE_ 0.125f

__device__ __forceinline__ float b2f(bf16 v) { return __bfloat162float(v); }
__device__ __forceinline__ bf16  f2b(float v) { return __float2bfloat16(v); }
__device__ __forceinline__ float us2f(unsigned short u) {
    return __uint_as_float(((unsigned int)u) << 16);
}
__device__ __forceinline__ unsigned short f2bu(float v) {
    bf16 t = __float2bfloat16(v);
    return *reinterpret_cast<unsigned short*>(&t);
}
__device__ __forceinline__ float ldf(const float* p) { return *p; }
__device__ __forceinline__ float ldf(const bf16* p)  { return __bfloat162float(*p); }
__device__ __forceinline__ void stf(float* p, float v) { *p = v; }
__device__ __forceinline__ void stf(bf16* p, float v)  { *p = f2b(v); }
#define MFMA16(a, b, c) __builtin_amdgcn_mfma_f32_16x16x32_bf16((a), (b), (c), 0, 0, 0)

// Async global->LDS, 16B per lane. LDS dest is wave-uniform base + lane*16.
__device__ __forceinline__ void gl16(const unsigned short* g, unsigned short* l) {
    __builtin_amdgcn_global_load_lds(
        (const __attribute__((address_space(1))) unsigned int*)g,
        (__attribute__((address_space(3))) unsigned int*)l, 16, 0, 0);
}

// ---------------------------------------------------------------------------
// Transpose-pack: W[K][N] fp32 -> W^T[n][k] bf16 at dst+dbase, row stride drow.
// ---------------------------------------------------------------------------
struct PackT {
    const float* src[12];
    unsigned K[12], N[12], dbase[12], drow[12];
    unsigned t0[13];
};

__global__ __launch_bounds__(256) void packT_kernel(PackT pa, bf16* __restrict__ dst)
{
    int bid = blockIdx.x, s = 0;
    while (s < 11 && bid >= (int)pa.t0[s + 1]) s++;
    int t = bid - (int)pa.t0[s];
    unsigned K = pa.K[s], N = pa.N[s];
    unsigned ntk = K >> 5;
    unsigned k0 = (t % ntk) << 5, n0 = (t / ntk) << 6;
    __shared__ float tile[32][65];
    const float* src = pa.src[s];
    int tid = threadIdx.x;
    {
        int e = tid * 8, k = e >> 6, n = e & 63;
        const float* p = src + (size_t)(k0 + k) * N + n0 + n;
#pragma unroll
        for (int j = 0; j < 8; j++) tile[k][n + j] = p[j];
    }
    __syncthreads();
    {
        int f = tid * 8, n = f >> 5, k = f & 31;
        bf16* q = dst + (size_t)pa.dbase[s] + (size_t)(n0 + n) * pa.drow[s] + k0 + k;
#pragma unroll
        for (int j = 0; j < 8; j++) q[j] = f2b(tile[k + j][n]);
    }
}

// ---------------------------------------------------------------------------
// Full LayerNorm over D_=768 -> bf16 out. One wave per row.
// ---------------------------------------------------------------------------
template <typename T>
__global__ __launch_bounds__(64) void lnfull_kernel(
    const T* __restrict__ in, const float* __restrict__ g,
    const float* __restrict__ b, bf16* __restrict__ out)
{
    int row = blockIdx.x, lane = threadIdx.x;
    const T* p = in + (size_t)row * D_;
    float v[12];
    float s = 0.f;
#pragma unroll
    for (int i = 0; i < 12; i++) { v[i] = ldf(p + lane + i * 64); s += v[i]; }
#pragma unroll
    for (int o = 32; o > 0; o >>= 1) s += __shfl_down(s, o);
    float mean = __shfl(s, 0) * (1.f / 768.f);
    float var = 0.f;
#pragma unroll
    for (int i = 0; i < 12; i++) { float d = v[i] - mean; var += d * d; }
#pragma unroll
    for (int o = 32; o > 0; o >>= 1) var += __shfl_down(var, o);
    float rstd = rsqrtf(__shfl(var, 0) * (1.f / 768.f) + 1e-5f);
    bf16* q = out + (size_t)row * D_;
#pragma unroll
    for (int i = 0; i < 12; i++) {
        int c = lane + i * 64;
        q[c] = f2b((v[i] - mean) * rstd * g[c] + b[c]);
    }
}

// ---------------------------------------------------------------------------
// MFMA bf16 GEMM, 128x128 tile, BK=64, XCD-swizzled blocks (m97 structure).
// AM: 0 = bf16 A via global_load_lds; 1 = fp32 A reg-staged; 2 = bf16 A
// summed over 4 fixed-stride slabs (reg-staged). B always global_load_lds.
// Requires M%128==0, N%128==0, K%64==0.
// Split epilogue: Cq (n<512, x sscale; Cq2 = v*SCALE_+qbias2) / Cv (n>=512),
// head-major panels with vshift = log2(rows per batch).
// ---------------------------------------------------------------------------
template <int AM, typename TC, typename TR>
__global__ __launch_bounds__(256, 4) void mgemm128_kernel(
    const void* __restrict__ Av, const bf16* __restrict__ BwT,
    TC* __restrict__ C, int M, int N, int K,
    const float* __restrict__ bias, int relu, const TR* __restrict__ res,
    bf16* __restrict__ Cq, bf16* __restrict__ Cv,
    bf16* __restrict__ Cq2, const float* __restrict__ qbias2,
    float sscale, int vshift)
{
    __shared__ __align__(16) unsigned short As[128 * 64];
    __shared__ __align__(16) unsigned short Bs[128 * 64];
    int tid = threadIdx.x, wave = tid >> 6, lane = tid & 63;
    int lc = lane & 15, kq = lane >> 4;
    int wm = (wave & 1) * 64, wn = (wave >> 1) * 64;
    // XCD-aware bijective swizzle (nwg % 8 == 0 for all launches)
    int nbx = gridDim.x, nwg = nbx * gridDim.y;
    int bid = blockIdx.y * nbx + blockIdx.x;
    int sbid = (nwg & 7) ? bid : ((bid & 7) * (nwg >> 3) + (bid >> 3));
    int bm = (sbid / nbx) * 128, bn = (sbid % nbx) * 128;
    f32x4 acc[4][4] = {};
    int grow = tid >> 3, gcol = (tid & 7) * 8;
    const unsigned short* bg = (const unsigned short*)BwT + (size_t)(bn + grow) * K + gcol;
    unsigned short* asl = As + wave * 512;
    unsigned short* bsl = Bs + wave * 512;
    const size_t SL = (size_t)B_ * N2_ * 768;

    for (int k0 = 0; k0 < K; k0 += 64) {
        if (AM == 0) {
            const unsigned short* ag = (const unsigned short*)Av + (size_t)(bm + grow) * K + k0 + gcol;
#pragma unroll
            for (int it = 0; it < 4; it++)
                gl16(ag + (size_t)(it * 32) * K, asl + it * 2048);
        } else if (AM == 1) {
            const float* ap = (const float*)Av + (size_t)(bm + grow) * K + k0 + gcol;
#pragma unroll
            for (int it = 0; it < 4; it++) {
                const float* p = ap + (size_t)(it * 32) * K;
                s16x8 w;
#pragma unroll
                for (int j = 0; j < 8; j++) w[j] = (short)f2bu(p[j]);
                *reinterpret_cast<s16x8*>(&As[(grow + it * 32) * 64 + gcol]) = w;
            }
        } else {
#pragma unroll
            for (int it = 0; it < 4; it++) {
                const unsigned short* a0 = (const unsigned short*)Av
                    + (size_t)(bm + grow + it * 32) * K + k0 + gcol;
                s16x8 v0 = *reinterpret_cast<const s16x8*>(a0);
                s16x8 v1 = *reinterpret_cast<const s16x8*>(a0 + SL);
                s16x8 v2 = *reinterpret_cast<const s16x8*>(a0 + 2 * SL);
                s16x8 v3 = *reinterpret_cast<const s16x8*>(a0 + 3 * SL);
                s16x8 w;
#pragma unroll
                for (int j = 0; j < 8; j++)
                    w[j] = (short)f2bu(us2f((unsigned short)v0[j]) + us2f((unsigned short)v1[j]) +
                                       us2f((unsigned short)v2[j]) + us2f((unsigned short)v3[j]));
                *reinterpret_cast<s16x8*>(&As[(grow + it * 32) * 64 + gcol]) = w;
            }
        }
#pragma unroll
        for (int it = 0; it < 4; it++)
            gl16(bg + (size_t)(it * 32) * K + k0, bsl + it * 2048);
        __syncthreads();
#pragma unroll
        for (int kh = 0; kh < 2; kh++) {
            s16x8 af[4], bf[4];
#pragma unroll
            for (int mt = 0; mt < 4; mt++)
                af[mt] = *reinterpret_cast<const s16x8*>(&As[(wm + mt * 16 + lc) * 64 + kh * 32 + kq * 8]);
#pragma unroll
            for (int nt = 0; nt < 4; nt++)
                bf[nt] = *reinterpret_cast<const s16x8*>(&Bs[(wn + nt * 16 + lc) * 64 + kh * 32 + kq * 8]);
#pragma unroll
            for (int mt = 0; mt < 4; mt++)
#pragma unroll
                for (int nt = 0; nt < 4; nt++)
                    acc[mt][nt] = MFMA16(af[mt], bf[nt], acc[mt][nt]);
        }
        __syncthreads();
    }

#pragma unroll
    for (int mt = 0; mt < 4; mt++) {
#pragma unroll
        for (int nt = 0; nt < 4; nt++) {
            int n = bn + wn + nt * 16 + lc;
            float bv = (!Cq && bias) ? bias[n] : 0.f;
#pragma unroll
            for (int r = 0; r < 4; r++) {
                int m = bm + wm + mt * 16 + kq * 4 + r;
                float vr = acc[mt][nt][r];
                if (Cq) {
                    int rows = 1 << vshift;
                    int bb = m >> vshift, rr = m & (rows - 1);
                    if (n < 512) {
                        size_t off = (((size_t)bb * 8 + (n >> 6)) * rows + rr) * 64 + (n & 63);
                        Cq[off] = f2b(vr * sscale);
                        if (Cq2) Cq2[off] = f2b(vr * SCALE_ + qbias2[n]);
                    } else {
                        int nn = n - 512, hh = nn / 96, dv = nn - hh * 96;
                        Cv[(((size_t)bb * 8 + hh) * rows + rr) * 96 + dv] = f2b(vr);
                    }
                } else {
                    float v = vr + bv;
                    if (relu) v = fmaxf(v, 0.f);
                    size_t off = (size_t)m * N + n;
                    if (res) v += ldf(res + off);
                    stf(C + off, v);
                }
            }
        }
    }
}

// ---------------------------------------------------------------------------
// MFMA bf16 GEMM, 64x64 tile, BK=32 (only for REL: M=4095, K=96).
// ---------------------------------------------------------------------------
__global__ __launch_bounds__(256) void mgemm64_kernel(
    const void* __restrict__ Av, const bf16* __restrict__ BwT,
    bf16* __restrict__ C, int M, int N, int K)
{
    __shared__ __align__(16) unsigned short As[64 * 32];
    __shared__ __align__(16) unsigned short Bs[64 * 32];
    int tid = threadIdx.x, wave = tid >> 6, lane = tid & 63;
    int nbx = gridDim.x, nwg = nbx * gridDim.y;
    int bid = blockIdx.y * nbx + blockIdx.x;
    int sbid = (nwg & 7) ? bid : ((bid & 7) * (nwg >> 3) + (bid >> 3));
    int bm = (sbid / nbx) * 64, bn = (sbid % nbx) * 64;
    f32x4 acc[4] = {};
    int grow = tid >> 2, gcol = (tid & 3) * 8;
    const unsigned short* bg = (const unsigned short*)BwT + (size_t)(bn + grow) * K + gcol;
    unsigned short* asl = As + wave * 512;
    unsigned short* bsl = Bs + wave * 512;

    for (int k0 = 0; k0 < K; k0 += 32) {
        gl16((const unsigned short*)Av + (size_t)(bm + grow) * K + k0 + gcol, asl);
        gl16(bg + k0, bsl);
        __syncthreads();
        s16x8 afrag = *reinterpret_cast<const s16x8*>(&As[(wave * 16 + (lane & 15)) * 32 + (lane >> 4) * 8]);
#pragma unroll
        for (int ns = 0; ns < 4; ns++) {
            s16x8 bfrag = *reinterpret_cast<const s16x8*>(&Bs[(ns * 16 + (lane & 15)) * 32 + (lane >> 4) * 8]);
            acc[ns] = MFMA16(afrag, bfrag, acc[ns]);
        }
        __syncthreads();
    }

    int col = lane & 15, rg = (lane >> 4) * 4;
#pragma unroll
    for (int ns = 0; ns < 4; ns++) {
        int n = bn + ns * 16 + col;
#pragma unroll
        for (int r = 0; r < 4; r++) {
            int m = bm + wave * 16 + rg + r;
            if (m >= M) continue;
            C[(size_t)m * N + n] = f2b(acc[ns][r]);
        }
    }
}

// ---------------------------------------------------------------------------
// Enformer positional features: pos[4095, 96] bf16.
// ---------------------------------------------------------------------------
__global__ __launch_bounds__(64) void pos_kernel(bf16* __restrict__ pos)
{
    int m = blockIdx.x * 64 + threadIdx.x;
    if (m >= NPOS_) return;
    float dist = (float)(m - 2047);
    float ad = fabsf(dist);
    float sgn = (dist > 0.f) ? 1.f : ((dist < 0.f) ? -1.f : 0.f);
    float f[48];
#pragma unroll
    for (int t = 0; t < 16; t++) {
        float hl = exp2f(3.f + (8.f / 15.f) * (float)t);
        f[t] = expf(-0.69314718056f / hl * ad);
    }
#pragma unroll
    for (int t = 0; t < 16; t++) {
        float cw = exp2f((float)(t + 1)) - 1.f;
        f[16 + t] = (cw > ad) ? 1.f : 0.f;
    }
    float pr[16];
    float mx = 0.f;
    if (ad < 0.5f) {
#pragma unroll
        for (int t = 0; t < 16; t++) pr[t] = 1e-8f;
        mx = 1e-8f;
    } else {
        float lad = logf(ad);
#pragma unroll
        for (int t = 0; t < 16; t++) {
            float mean = 128.f * (float)(t + 1);
            float cc = (mean / 64.f) * (mean / 64.f);
            float rate = mean * (1.f / 4096.f);
            float logp = (cc - 1.f) * lad - rate * ad - (lgammaf(cc) - cc * logf(rate));
            float p = expf(logp) + 1e-8f;
            pr[t] = p;
            mx = fmaxf(mx, p);
        }
    }
#pragma unroll
    for (int t = 0; t < 16; t++) f[32 + t] = pr[t] / mx;

    bf16* o = pos + (size_t)m * 96;
#pragma unroll
    for (int c = 0; c < 48; c++) { o[c] = f2b(f[c]); o[48 + c] = f2b(sgn * f[c]); }
}

// ---------------------------------------------------------------------------
// Shifted rel precompute: Tsh[bh][j][i] = dot(kbb[bh,j,:], relq[i-j+511,:]),
// i in [base, base+plen), row pitch plen. Block: 64 j x 256 m super-tile;
// diagonal assembled in LDS (i-space), stored as aligned contiguous chunks.
// ---------------------------------------------------------------------------
#define TP_ 344
__global__ __launch_bounds__(256) void tshift_kernel(
    const bf16* __restrict__ kbb, const bf16* __restrict__ relq,
    bf16* __restrict__ tsh, int base, int plen)
{
    int mc = blockIdx.x, jt = blockIdx.y, bh = blockIdx.z;
    int mbase = mc << 8, jg0 = jt << 6, h = bh & 7;
    int iwin0 = mbase + jg0 - 511 - base;   // global i of (j=jg0, m=mbase)
    if (iwin0 + 318 < 0 || iwin0 >= plen) return;
    int a0 = iwin0 & 7;
    int iwa = iwin0 - a0;                   // aligned global i of LDS col 0
    __shared__ unsigned short Tl[64][TP_];
    int tid = threadIdx.x, wave = tid >> 6, lane = tid & 63;
    int lc = lane & 15, kq = lane >> 4;

    const bf16* ap = kbb + ((size_t)bh * N2_ + jg0 + wave * 16 + lc) * 64 + kq * 8;
    s16x8 af0 = *reinterpret_cast<const s16x8*>(ap);
    s16x8 af1 = *reinterpret_cast<const s16x8*>(ap + 32);

    int jrow = wave * 16 + kq * 4;          // + r = local j row
#pragma unroll
    for (int sub = 0; sub < 2; sub++) {
        int m0 = mbase + sub * 128;
        f32x4 tacc[8] = {};
#pragma unroll
        for (int ns = 0; ns < 8; ns++) {
            const bf16* rp = relq + (size_t)(m0 + ns * 16 + lc) * 512 + h * 64 + kq * 8;
            s16x8 rf0 = *reinterpret_cast<const s16x8*>(rp);
            s16x8 rf1 = *reinterpret_cast<const s16x8*>(rp + 32);
            tacc[ns] = MFMA16(af0, rf0, tacc[ns]);
            tacc[ns] = MFMA16(af1, rf1, tacc[ns]);
        }
#pragma unroll
        for (int ns = 0; ns < 8; ns++)
#pragma unroll
            for (int r = 0; r < 4; r++) {
                int col = sub * 128 + ns * 16 + lc + jrow + r + a0;  // <= 325
                Tl[jrow + r][col] = f2bu(tacc[ns][r]);
            }
    }
    __syncthreads();

    int row = tid >> 2, q = tid & 3;
    int cstart = row + a0;                  // valid cols: [cstart, cstart+256)
    bf16* out = tsh + ((size_t)bh * N2_ + jg0 + row) * (size_t)plen;
#pragma unroll
    for (int s = 0; s < 11; s++) {
        int c = (q + s * 4) * 8;            // 8-elem chunk, 16B aligned
        int i = iwa + c;
        if (c >= cstart && c + 8 <= cstart + 256 && i >= 0 && i + 8 <= plen) {
            *reinterpret_cast<s16x8*>(out + i) =
                *reinterpret_cast<const s16x8*>(&Tl[row][c]);
        } else {
#pragma unroll
            for (int e = 0; e < 8; e++) {
                int ce = c + e, ie = i + e;
                if (ce >= cstart && ce < cstart + 256 && ie >= 0 && ie < plen)
                    out[ie] = *reinterpret_cast<const bf16*>(&Tl[row][ce]);
            }
        }
    }
}

// ---------------------------------------------------------------------------
// MFMA attention pass 1: per 64 q-rows, flash over j. rel term streamed from
// precomputed Tsh (coalesced 64x64 tile stage). Head-major q/k/v.
// ---------------------------------------------------------------------------
__global__ __launch_bounds__(256) void attn1_kernel(
    const bf16* __restrict__ qb, const bf16* __restrict__ kb,
    const bf16* __restrict__ tsh, const bf16* __restrict__ v2,
    bf16* __restrict__ out1, float* __restrict__ mst, float* __restrict__ lst,
    int base, int tpitch)
{
    int bh = blockIdx.y;
    int b = bh >> 3, h = bh & 7;
    int i0 = base + blockIdx.x * 64;
    __shared__ __align__(16) unsigned short Ts[64][72];
    __shared__ __align__(16) unsigned short Ps[64][72];
    __shared__ __align__(16) unsigned short Vs[96][72];
    int tid = threadIdx.x, wave = tid >> 6, lane = tid & 63;
    int lc = lane & 15, kq = lane >> 4;
    int ibase = wave * 16 + kq * 4;

    const bf16* qp = qb + ((size_t)bh * N1_ + i0 + wave * 16 + lc) * 64 + kq * 8;
    s16x8 qf0 = *reinterpret_cast<const s16x8*>(qp);
    s16x8 qf1 = *reinterpret_cast<const s16x8*>(qp + 32);

    int trow = tid >> 2, tchunk = tid & 3;
    const unsigned short* tb0 = (const unsigned short*)tsh
        + ((size_t)bh * N2_ + trow) * tpitch + (i0 - base) + tchunk * 16;
    const unsigned short* vb0 = (const unsigned short*)v2
        + ((size_t)bh * N2_ + trow) * 96 + tchunk * 24;

    float m_run[4], l_run[4];
#pragma unroll
    for (int r = 0; r < 4; r++) { m_run[r] = -1e30f; l_run[r] = 0.f; }
    f32x4 oacc[6] = {};

    for (int j0 = 0; j0 < N2_; j0 += 64) {
        __syncthreads();
        {
            const unsigned short* p = tb0 + (size_t)j0 * tpitch;
            *reinterpret_cast<s16x8*>(&Ts[trow][tchunk * 16]) =
                *reinterpret_cast<const s16x8*>(p);
            *reinterpret_cast<s16x8*>(&Ts[trow][tchunk * 16 + 8]) =
                *reinterpret_cast<const s16x8*>(p + 8);
        }
        {
            const unsigned short* p = vb0 + (size_t)j0 * 96;
            s16x8 w0 = *reinterpret_cast<const s16x8*>(p);
            s16x8 w1 = *reinterpret_cast<const s16x8*>(p + 8);
            s16x8 w2 = *reinterpret_cast<const s16x8*>(p + 16);
            int vd = tchunk * 24;
#pragma unroll
            for (int s = 0; s < 8; s++) Vs[vd + s][trow] = (unsigned short)w0[s];
#pragma unroll
            for (int s = 0; s < 8; s++) Vs[vd + 8 + s][trow] = (unsigned short)w1[s];
#pragma unroll
            for (int s = 0; s < 8; s++) Vs[vd + 16 + s][trow] = (unsigned short)w2[s];
        }
        __syncthreads();

        f32x4 cacc[4] = {};
#pragma unroll
        for (int ns = 0; ns < 4; ns++) {
            const bf16* kp = kb + ((size_t)bh * N2_ + j0 + ns * 16 + lc) * 64 + kq * 8;
            s16x8 kf0 = *reinterpret_cast<const s16x8*>(kp);
            s16x8 kf1 = *reinterpret_cast<const s16x8*>(kp + 32);
            cacc[ns] = MFMA16(qf0, kf0, cacc[ns]);
            cacc[ns] = MFMA16(qf1, kf1, cacc[ns]);
        }
        float Lv[4][4];
#pragma unroll
        for (int ns = 0; ns < 4; ns++) {
            int jloc = ns * 16 + lc;
            s16x4 tv = *reinterpret_cast<const s16x4*>(&Ts[jloc][ibase]);
#pragma unroll
            for (int r = 0; r < 4; r++)
                Lv[ns][r] = cacc[ns][r] + us2f((unsigned short)tv[r]);
        }
#pragma unroll
        for (int r = 0; r < 4; r++) {
            float v = fmaxf(fmaxf(Lv[0][r], Lv[1][r]), fmaxf(Lv[2][r], Lv[3][r]));
            v = fmaxf(v, __shfl_xor(v, 1));
            v = fmaxf(v, __shfl_xor(v, 2));
            v = fmaxf(v, __shfl_xor(v, 4));
            v = fmaxf(v, __shfl_xor(v, 8));
            float mn = fmaxf(m_run[r], v);
            float alpha = __expf(m_run[r] - mn);
            m_run[r] = mn;
            float s = 0.f;
#pragma unroll
            for (int ns = 0; ns < 4; ns++) {
                float p = __expf(Lv[ns][r] - mn);
                Lv[ns][r] = p;
                s += p;
            }
            s += __shfl_xor(s, 1);
            s += __shfl_xor(s, 2);
            s += __shfl_xor(s, 4);
            s += __shfl_xor(s, 8);
            l_run[r] = l_run[r] * alpha + s;
#pragma unroll
            for (int ns6 = 0; ns6 < 6; ns6++) oacc[ns6][r] *= alpha;
        }
#pragma unroll
        for (int ns = 0; ns < 4; ns++)
#pragma unroll
            for (int r = 0; r < 4; r++)
                Ps[ibase + r][ns * 16 + lc] = f2bu(Lv[ns][r]);
#pragma unroll
        for (int kk = 0; kk < 2; kk++) {
            s16x8 pf = *reinterpret_cast<const s16x8*>(&Ps[wave * 16 + lc][kq * 8 + kk * 32]);
#pragma unroll
            for (int ns6 = 0; ns6 < 6; ns6++) {
                s16x8 vf = *reinterpret_cast<const s16x8*>(&Vs[ns6 * 16 + lc][kq * 8 + kk * 32]);
                oacc[ns6] = MFMA16(pf, vf, oacc[ns6]);
            }
        }
    }

    float invl[4];
#pragma unroll
    for (int r = 0; r < 4; r++) invl[r] = 1.f / l_run[r];
#pragma unroll
    for (int ns6 = 0; ns6 < 6; ns6++)
#pragma unroll
        for (int r = 0; r < 4; r++)
            out1[(size_t)(b * N1_ + i0 + ibase + r) * 768 + h * 96 + ns6 * 16 + lc]
                = f2b(oacc[ns6][r] * invl[r]);
    if (lc == 0) {
#pragma unroll
        for (int r = 0; r < 4; r++) {
            mst[(size_t)bh * N1_ + i0 + ibase + r] = m_run[r];
            lst[(size_t)bh * N1_ + i0 + ibase + r] = l_run[r];
        }
    }
}

// ---------------------------------------------------------------------------
// MFMA attention pass 2: per 64 j-rows x 512-i quarter (blockIdx.z), writes
// quarter partials. rel term from Tsh; head-major q/k/v1.
// ---------------------------------------------------------------------------
__global__ __launch_bounds__(256) void attn2_kernel(
    const bf16* __restrict__ qb, const bf16* __restrict__ kb,
    const bf16* __restrict__ tsh, const bf16* __restrict__ v1,
    bf16* __restrict__ out2b, const float* __restrict__ mst,
    const float* __restrict__ lst, int base, int tpitch)
{
    int jt = blockIdx.x, bh = blockIdx.y;
    int b = bh >> 3, h = bh & 7;
    int ib = base + blockIdx.z * 512;
    bf16* out2 = out2b + (size_t)(ib >> 9) * ((size_t)B_ * N2_ * 768);
    int j0 = jt * 64;
    __shared__ __align__(16) unsigned short Ts[64][72];
    __shared__ __align__(16) unsigned short Ps[64][72];
    __shared__ __align__(16) unsigned short Vs[96][72];
    int tid = threadIdx.x, wave = tid >> 6, lane = tid & 63;
    int lc = lane & 15, kq = lane >> 4;
    int ibase = wave * 16 + kq * 4;

    s16x8 kf0[4], kf1[4];
#pragma unroll
    for (int ns = 0; ns < 4; ns++) {
        const bf16* kp = kb + ((size_t)bh * N2_ + j0 + ns * 16 + lc) * 64 + kq * 8;
        kf0[ns] = *reinterpret_cast<const s16x8*>(kp);
        kf1[ns] = *reinterpret_cast<const s16x8*>(kp + 32);
    }

    int trow = tid >> 2, tchunk = tid & 3;
    const unsigned short* tb0 = (const unsigned short*)tsh
        + ((size_t)bh * N2_ + j0 + trow) * tpitch + tchunk * 16;
    const unsigned short* vb0 = (const unsigned short*)v1
        + ((size_t)bh * N1_ + trow) * 96 + tchunk * 24;

    f32x4 oacc[6] = {};
    for (int i0 = ib; i0 < ib + 512; i0 += 64) {
        __syncthreads();
        {
            const unsigned short* p = tb0 + (i0 - base);
            *reinterpret_cast<s16x8*>(&Ts[trow][tchunk * 16]) =
                *reinterpret_cast<const s16x8*>(p);
            *reinterpret_cast<s16x8*>(&Ts[trow][tchunk * 16 + 8]) =
                *reinterpret_cast<const s16x8*>(p + 8);
        }
        {
            const unsigned short* p = vb0 + (size_t)i0 * 96;
            s16x8 w0 = *reinterpret_cast<const s16x8*>(p);
            s16x8 w1 = *reinterpret_cast<const s16x8*>(p + 8);
            s16x8 w2 = *reinterpret_cast<const s16x8*>(p + 16);
            int vd = tchunk * 24;
#pragma unroll
            for (int s = 0; s < 8; s++) Vs[vd + s][trow] = (unsigned short)w0[s];
#pragma unroll
            for (int s = 0; s < 8; s++) Vs[vd + 8 + s][trow] = (unsigned short)w1[s];
#pragma unroll
            for (int s = 0; s < 8; s++) Vs[vd + 16 + s][trow] = (unsigned short)w2[s];
        }
        __syncthreads();

        const bf16* qp = qb + ((size_t)bh * N1_ + i0 + wave * 16 + lc) * 64 + kq * 8;
        s16x8 qf0 = *reinterpret_cast<const s16x8*>(qp);
        s16x8 qf1 = *reinterpret_cast<const s16x8*>(qp + 32);
        f32x4 cacc[4] = {};
#pragma unroll
        for (int ns = 0; ns < 4; ns++) {
            cacc[ns] = MFMA16(qf0, kf0[ns], cacc[ns]);
            cacc[ns] = MFMA16(qf1, kf1[ns], cacc[ns]);
        }
        float mi[4], invli[4];
#pragma unroll
        for (int r = 0; r < 4; r++) {
            mi[r] = mst[(size_t)bh * N1_ + i0 + ibase + r];
            invli[r] = 1.f / lst[(size_t)bh * N1_ + i0 + ibase + r];
        }
#pragma unroll
        for (int ns = 0; ns < 4; ns++) {
            int jloc = ns * 16 + lc;
            s16x4 tv = *reinterpret_cast<const s16x4*>(&Ts[jloc][ibase]);
            s16x4 pw;
#pragma unroll
            for (int r = 0; r < 4; r++) {
                float L = cacc[ns][r] + us2f((unsigned short)tv[r]);
                pw[r] = (short)f2bu(__expf(L - mi[r]) * invli[r]);
            }
            *reinterpret_cast<s16x4*>(&Ps[jloc][ibase]) = pw;
        }
        __syncthreads();
#pragma unroll
        for (int kk = 0; kk < 2; kk++) {
            s16x8 pf = *reinterpret_cast<const s16x8*>(&Ps[wave * 16 + lc][kq * 8 + kk * 32]);
#pragma unroll
            for (int ns6 = 0; ns6 < 6; ns6++) {
                s16x8 vf = *reinterpret_cast<const s16x8*>(&Vs[ns6 * 16 + lc][kq * 8 + kk * 32]);
                oacc[ns6] = MFMA16(pf, vf, oacc[ns6]);
            }
        }
    }

#pragma unroll
    for (int ns6 = 0; ns6 < 6; ns6++)
#pragma unroll
        for (int r = 0; r < 4; r++)
            out2[(size_t)(b * N2_ + j0 + ibase + r) * 768 + h * 96 + ns6 * 16 + lc]
                = f2b(oacc[ns6][r]);
}

// ---------------------------------------------------------------------------
extern "C" void kernel_launch(void* const* d_in, const int* in_sizes, int n_in,
                              void* d_out, int out_size, void* d_ws, size_t ws_size,
                              hipStream_t stream)
{
    (void)in_sizes; (void)n_in; (void)out_size;
    const float* x      = (const float*)d_in[0];
    const float* y0     = (const float*)d_in[1];
    const float* Wres   = (const float*)d_in[2];
    const float* lnx_g  = (const float*)d_in[3];
    const float* lnx_b  = (const float*)d_in[4];
    const float* lny_g  = (const float*)d_in[5];
    const float* lny_b  = (const float*)d_in[6];
    const float* Wq     = (const float*)d_in[7];
    const float* Wk     = (const float*)d_in[8];
    const float* Wv1    = (const float*)d_in[9];
    const float* Wv2    = (const float*)d_in[10];
    const float* Wo1    = (const float*)d_in[11];
    const float* bo1    = (const float*)d_in[12];
    const float* Wo2    = (const float*)d_in[13];
    const float* bo2    = (const float*)d_in[14];
    const float* Wrel   = (const float*)d_in[15];
    const float* rel_pb = (const float*)d_in[16];
    const float* fx_g   = (const float*)d_in[17];
    const float* fx_b   = (const float*)d_in[18];
    const float* fx_w1  = (const float*)d_in[19];
    const float* fx_b1  = (const float*)d_in[20];
    const float* fx_w2  = (const float*)d_in[21];
    const float* fx_b2  = (const float*)d_in[22];
    const float* fy_g   = (const float*)d_in[23];
    const float* fy_b   = (const float*)d_in[24];
    const float* fy_w1  = (const float*)d_in[25];
    const float* fy_b1  = (const float*)d_in[26];
    const float* fy_w2  = (const float*)d_in[27];
    const float* fy_b2  = (const float*)d_in[28];

    float* out_x = (float*)d_out;                          // [4,2048,768] fp32
    float* out_y = out_x + (size_t)B_ * N1_ * D_;          // [4,512,768] fp32
    bf16* out1 = (bf16*)d_out;  // attn out1 parked in d_out (dies before fp32 writes)

    // ---- workspace ----
    char* W = (char*)d_ws;
    size_t o = 0;
    auto alloc = [&](size_t bytes) { char* p = W + o; o += (bytes + 255) & ~(size_t)255; return p; };
    bf16*   qb   = (bf16*)alloc((size_t)B_ * N1_ * 512 * 2);   // head-major [bh][2048][64]
    bf16*   kb   = (bf16*)alloc((size_t)B_ * N2_ * 512 * 2);   // [bh][512][64]
    bf16*   posb = (bf16*)alloc((size_t)NPOS_ * 96 * 2);
    bf16*   relq = (bf16*)alloc((size_t)NPOS_ * 512 * 2);
    bf16*   v1b  = (bf16*)alloc((size_t)B_ * N1_ * 768 * 2);   // [bh][2048][96]
    bf16*   hx2  = (bf16*)alloc((size_t)B_ * N1_ * 768 * 2);   // 4x out2 quarter slabs / hx
    bf16*   v2b  = (bf16*)alloc((size_t)B_ * N2_ * 768 * 2);   // [bh][512][96]
    float*  yb   = (float*)alloc((size_t)B_ * N2_ * 768 * 4);  // fp32 residual
    bf16*   kbbb = (bf16*)alloc((size_t)B_ * N2_ * 512 * 2);   // [bh][512][64]
    bf16*   wpool= (bf16*)alloc((size_t)9093120 * 2);          // W^T packed
    float*  mst  = (float*)alloc((size_t)B_ * H_ * N1_ * 4);
    float*  lst  = (float*)alloc((size_t)B_ * H_ * N1_ * 4);

    // Tsh / x1 / y1 time-share the tail region (x1,y1 dead during attention).
    size_t x1y1 = ((size_t)B_ * N1_ * 768 + (size_t)B_ * N2_ * 768) * 2;  // 15.73 MB
    size_t rem = ws_size > o ? ws_size - o : 0;
    int plen = 512;
    if (rem >= (size_t)32 * 512 * 2048 * 2 + 1024) plen = 2048;
    else if (rem >= (size_t)32 * 512 * 1024 * 2 + 1024) plen = 1024;
    size_t tshB = (size_t)32 * 512 * (size_t)plen * 2;
    bf16* tshb = (bf16*)alloc(tshB > x1y1 ? tshB : x1y1);
    bf16* x1 = tshb;
    bf16* y1 = x1 + (size_t)B_ * N1_ * 768;

    bf16* x4 = qb;            // after attention, qb..relq span is dead
    bf16* y4 = v2b;
    bf16* hx = v1b;           // FFNx hidden spans v1b+hx2
    bf16* out2h = hx2;        // 4 quarter slabs (3.15MB each) inside hx2
    bf16* hy = v1b;
    bf16* x4ln = x1;          // Tsh dead by step 7
    bf16* y4ln = y1;

    // packed W^T offsets (elements)
    const unsigned OW_RES = 0, OW_QV1 = 1179648, OW_KV2 = 2162688, OW_O1 = 3145728,
                   OW_O2 = 3735552, OW_REL = 4325376, OW_FXW1 = 4374528,
                   OW_FXW2 = 5554176, OW_FYW1 = 6733824, OW_FYW2 = 7913472;

    PackT pa;
    const float* srcs[12] = {Wres, Wq, Wv1, Wk, Wv2, Wo1, Wo2, Wrel,
                             fx_w1, fx_w2, fy_w1, fy_w2};
    unsigned Ks[12] = {1536, 768, 768, 768, 768, 768, 768, 96, 768, 1536, 768, 1536};
    unsigned Nss[12] = {768, 512, 768, 512, 768, 768, 768, 512, 1536, 768, 1536, 768};
    unsigned dbs[12] = {OW_RES, OW_QV1, OW_QV1 + 393216, OW_KV2, OW_KV2 + 393216,
                        OW_O1, OW_O2, OW_REL, OW_FXW1, OW_FXW2, OW_FYW1, OW_FYW2};
    unsigned drs[12] = {1536, 768, 768, 768, 768, 768, 768, 96, 768, 1536, 768, 1536};
    unsigned cum = 0;
    for (int i = 0; i < 12; i++) {
        pa.src[i] = srcs[i]; pa.K[i] = Ks[i]; pa.N[i] = Nss[i];
        pa.dbase[i] = dbs[i]; pa.drow[i] = drs[i];
        pa.t0[i] = cum;
        cum += (Ks[i] >> 5) * (Nss[i] >> 6);
    }
    pa.t0[12] = cum;

    dim3 blk(256);
    // 0. transpose-pack weights
    packT_kernel<<<cum, blk, 0, stream>>>(pa, wpool);
    // 1. y = y0 @ W_res (fp32 A path, fp32 out)
    mgemm128_kernel<1, float, float><<<dim3(6, 16), blk, 0, stream>>>(
        y0, wpool + OW_RES, yb, B_ * N2_, D_, 1536,
        nullptr, 0, nullptr, nullptr, nullptr, nullptr, nullptr, 0.f, 0);
    // 2. LayerNorms materialized as bf16
    lnfull_kernel<float><<<B_ * N1_, 64, 0, stream>>>(x, lnx_g, lnx_b, x1);
    lnfull_kernel<float><<<B_ * N2_, 64, 0, stream>>>(yb, lny_g, lny_b, y1);
    // 3. fused projections [q|v1], [k|v2]+kbb -> head-major panels
    mgemm128_kernel<0, bf16, float><<<dim3(10, 64), blk, 0, stream>>>(
        x1, wpool + OW_QV1, (bf16*)nullptr, B_ * N1_, 1280, D_,
        nullptr, 0, nullptr, qb, v1b, nullptr, nullptr, SCALE_, 11);
    mgemm128_kernel<0, bf16, float><<<dim3(10, 16), blk, 0, stream>>>(
        y1, wpool + OW_KV2, (bf16*)nullptr, B_ * N2_, 1280, D_,
        nullptr, 0, nullptr, kb, v2b, kbbb, rel_pb, 1.f, 9);
    // 4. positional features + rel_q
    pos_kernel<<<(NPOS_ + 63) / 64, 64, 0, stream>>>(posb);
    mgemm64_kernel<<<dim3(8, 64), blk, 0, stream>>>(
        posb, wpool + OW_REL, relq, NPOS_, 512, 96);
    // 5. shifted-rel precompute + attention, phased to fit workspace
    for (int base = 0; base < N1_; base += plen) {
        tshift_kernel<<<dim3(10, 8, 32), blk, 0, stream>>>(kbbb, relq, tshb, base, plen);
        attn1_kernel<<<dim3(plen / 64, 32), blk, 0, stream>>>(
            qb, kb, tshb, v2b, out1, mst, lst, base, plen);
        attn2_kernel<<<dim3(8, 32, plen / 512), blk, 0, stream>>>(
            qb, kb, tshb, v1b, out2h, mst, lst, base, plen);
    }
    // 6. output projections + residuals (O2 sums the 4 quarter slabs)
    mgemm128_kernel<0, bf16, float><<<dim3(6, 64), blk, 0, stream>>>(
        out1, wpool + OW_O1, x4, B_ * N1_, D_, D_,
        bo1, 0, x, nullptr, nullptr, nullptr, nullptr, 0.f, 0);
    mgemm128_kernel<2, bf16, float><<<dim3(6, 16), blk, 0, stream>>>(
        out2h, wpool + OW_O2, y4, B_ * N2_, D_, D_,
        bo2, 0, yb, nullptr, nullptr, nullptr, nullptr, 0.f, 0);
    // 7. FFN x -> out_x fp32
    lnfull_kernel<bf16><<<B_ * N1_, 64, 0, stream>>>(x4, fx_g, fx_b, x4ln);
    mgemm128_kernel<0, bf16, float><<<dim3(12, 64), blk, 0, stream>>>(
        x4ln, wpool + OW_FXW1, hx, B_ * N1_, 1536, D_,
        fx_b1, 1, nullptr, nullptr, nullptr, nullptr, nullptr, 0.f, 0);
    mgemm128_kernel<0, float, bf16><<<dim3(6, 64), blk, 0, stream>>>(
        hx, wpool + OW_FXW2, out_x, B_ * N1_, D_, 1536,
        fx_b2, 0, x4, nullptr, nullptr, nullptr, nullptr, 0.f, 0);
    // 8. FFN y -> out_y fp32
    lnfull_kernel<bf16><<<B_ * N2_, 64, 0, stream>>>(y4, fy_g, fy_b, y4ln);
    mgemm128_kernel<0, bf16, float><<<dim3(12, 16), blk, 0, stream>>>(
        y4ln, wpool + OW_FYW1, hy, B_ * N2_, 1536, D_,
        fy_b1, 1, nullptr, nullptr, nullptr, nullptr, nullptr, 0.f, 0);
    mgemm128_kernel<0, float, bf16><<<dim3(6, 16), blk, 0, stream>>>(
        hy, wpool + OW_FYW2, out_y, B_ * N2_, D_, 1536,
        fy_b2, 0, y4, nullptr, nullptr, nullptr, nullptr, 0.f, 0);
}

// Round 5
// 600.377 us; speedup vs baseline: 1.4173x; 1.4173x over previous
//
#include <hip/hip_runtime.h>
#include <hip/hip_bf16.h>
#include <math.h>

typedef __hip_bfloat16 bf16;
typedef short s16x8 __attribute__((ext_vector_type(8)));
typedef short s16x4 __attribute__((ext_vector_type(4)));
typedef float f32x4 __attribute__((ext_vector_type(4)));

#define B_    4
#define N1_   2048
#define N2_   512
#define D_    768
#define H_    8
#define DK_   64
#define DV_   96
#define NPOS_ 4095
#define SCALE_ 0.125f

__device__ __forceinline__ float b2f(bf16 v) { return __bfloat162float(v); }
__device__ __forceinline__ bf16  f2b(float v) { return __float2bfloat16(v); }
__device__ __forceinline__ float us2f(unsigned short u) {
    return __uint_as_float(((unsigned int)u) << 16);
}
__device__ __forceinline__ unsigned short f2bu(float v) {
    bf16 t = __float2bfloat16(v);
    return *reinterpret_cast<unsigned short*>(&t);
}
__device__ __forceinline__ float ldf(const float* p) { return *p; }
__device__ __forceinline__ float ldf(const bf16* p)  { return __bfloat162float(*p); }
__device__ __forceinline__ void stf(float* p, float v) { *p = v; }
__device__ __forceinline__ void stf(bf16* p, float v)  { *p = f2b(v); }
#define MFMA16(a, b, c) __builtin_amdgcn_mfma_f32_16x16x32_bf16((a), (b), (c), 0, 0, 0)

// Async global->LDS, 16B per lane. LDS dest is wave-uniform base + lane*16.
__device__ __forceinline__ void gl16(const unsigned short* g, unsigned short* l) {
    __builtin_amdgcn_global_load_lds(
        (const __attribute__((address_space(1))) unsigned int*)g,
        (__attribute__((address_space(3))) unsigned int*)l, 16, 0, 0);
}

// ---------------------------------------------------------------------------
// Transpose-pack: W[K][N] fp32 -> W^T[n][k] bf16 at dst+dbase, row stride drow.
// ---------------------------------------------------------------------------
struct PackT {
    const float* src[12];
    unsigned K[12], N[12], dbase[12], drow[12];
    unsigned t0[13];
};

__global__ __launch_bounds__(256) void packT_kernel(PackT pa, bf16* __restrict__ dst)
{
    int bid = blockIdx.x, s = 0;
    while (s < 11 && bid >= (int)pa.t0[s + 1]) s++;
    int t = bid - (int)pa.t0[s];
    unsigned K = pa.K[s], N = pa.N[s];
    unsigned ntk = K >> 5;
    unsigned k0 = (t % ntk) << 5, n0 = (t / ntk) << 6;
    __shared__ float tile[32][65];
    const float* src = pa.src[s];
    int tid = threadIdx.x;
    {
        int e = tid * 8, k = e >> 6, n = e & 63;
        const float* p = src + (size_t)(k0 + k) * N + n0 + n;
#pragma unroll
        for (int j = 0; j < 8; j++) tile[k][n + j] = p[j];
    }
    __syncthreads();
    {
        int f = tid * 8, n = f >> 5, k = f & 31;
        bf16* q = dst + (size_t)pa.dbase[s] + (size_t)(n0 + n) * pa.drow[s] + k0 + k;
#pragma unroll
        for (int j = 0; j < 8; j++) q[j] = f2b(tile[k + j][n]);
    }
}

// ---------------------------------------------------------------------------
// Full LayerNorm over D_=768 -> bf16 out. One wave per row.
// ---------------------------------------------------------------------------
template <typename T>
__global__ __launch_bounds__(64) void lnfull_kernel(
    const T* __restrict__ in, const float* __restrict__ g,
    const float* __restrict__ b, bf16* __restrict__ out)
{
    int row = blockIdx.x, lane = threadIdx.x;
    const T* p = in + (size_t)row * D_;
    float v[12];
    float s = 0.f;
#pragma unroll
    for (int i = 0; i < 12; i++) { v[i] = ldf(p + lane + i * 64); s += v[i]; }
#pragma unroll
    for (int o = 32; o > 0; o >>= 1) s += __shfl_down(s, o);
    float mean = __shfl(s, 0) * (1.f / 768.f);
    float var = 0.f;
#pragma unroll
    for (int i = 0; i < 12; i++) { float d = v[i] - mean; var += d * d; }
#pragma unroll
    for (int o = 32; o > 0; o >>= 1) var += __shfl_down(var, o);
    float rstd = rsqrtf(__shfl(var, 0) * (1.f / 768.f) + 1e-5f);
    bf16* q = out + (size_t)row * D_;
#pragma unroll
    for (int i = 0; i < 12; i++) {
        int c = lane + i * 64;
        q[c] = f2b((v[i] - mean) * rstd * g[c] + b[c]);
    }
}

// ---------------------------------------------------------------------------
// 128x128 GEMM body (m97 structure), called by the dual-problem kernel.
// AM: 0 = bf16 A via global_load_lds; 2 = bf16 A summed over 4 slabs.
// ---------------------------------------------------------------------------
template <int AM, typename TC, typename TR>
__device__ __forceinline__ void gemm128_body(
    unsigned short* As, unsigned short* Bs, int tid,
    const void* Av, const bf16* BwT, TC* C, int M, int N, int K,
    const float* bias, int relu, const TR* res,
    bf16* Cq, bf16* Cv, bf16* Cq2, const float* qbias2,
    float sscale, int vshift, int bm, int bn)
{
    int wave = tid >> 6, lane = tid & 63;
    int lc = lane & 15, kq = lane >> 4;
    int wm = (wave & 1) * 64, wn = (wave >> 1) * 64;
    f32x4 acc[4][4] = {};
    int grow = tid >> 3, gcol = (tid & 7) * 8;
    const unsigned short* bg = (const unsigned short*)BwT + (size_t)(bn + grow) * K + gcol;
    unsigned short* asl = As + wave * 512;
    unsigned short* bsl = Bs + wave * 512;
    const size_t SL = (size_t)B_ * N2_ * 768;

    for (int k0 = 0; k0 < K; k0 += 64) {
        if (AM == 0) {
            const unsigned short* ag = (const unsigned short*)Av + (size_t)(bm + grow) * K + k0 + gcol;
#pragma unroll
            for (int it = 0; it < 4; it++)
                gl16(ag + (size_t)(it * 32) * K, asl + it * 2048);
        } else {
#pragma unroll
            for (int it = 0; it < 4; it++) {
                const unsigned short* a0 = (const unsigned short*)Av
                    + (size_t)(bm + grow + it * 32) * K + k0 + gcol;
                s16x8 v0 = *reinterpret_cast<const s16x8*>(a0);
                s16x8 v1 = *reinterpret_cast<const s16x8*>(a0 + SL);
                s16x8 v2 = *reinterpret_cast<const s16x8*>(a0 + 2 * SL);
                s16x8 v3 = *reinterpret_cast<const s16x8*>(a0 + 3 * SL);
                s16x8 w;
#pragma unroll
                for (int j = 0; j < 8; j++)
                    w[j] = (short)f2bu(us2f((unsigned short)v0[j]) + us2f((unsigned short)v1[j]) +
                                       us2f((unsigned short)v2[j]) + us2f((unsigned short)v3[j]));
                *reinterpret_cast<s16x8*>(&As[(grow + it * 32) * 64 + gcol]) = w;
            }
        }
#pragma unroll
        for (int it = 0; it < 4; it++)
            gl16(bg + (size_t)(it * 32) * K + k0, bsl + it * 2048);
        __syncthreads();
#pragma unroll
        for (int kh = 0; kh < 2; kh++) {
            s16x8 af[4], bf[4];
#pragma unroll
            for (int mt = 0; mt < 4; mt++)
                af[mt] = *reinterpret_cast<const s16x8*>(&As[(wm + mt * 16 + lc) * 64 + kh * 32 + kq * 8]);
#pragma unroll
            for (int nt = 0; nt < 4; nt++)
                bf[nt] = *reinterpret_cast<const s16x8*>(&Bs[(wn + nt * 16 + lc) * 64 + kh * 32 + kq * 8]);
#pragma unroll
            for (int mt = 0; mt < 4; mt++)
#pragma unroll
                for (int nt = 0; nt < 4; nt++)
                    acc[mt][nt] = MFMA16(af[mt], bf[nt], acc[mt][nt]);
        }
        __syncthreads();
    }

#pragma unroll
    for (int mt = 0; mt < 4; mt++) {
#pragma unroll
        for (int nt = 0; nt < 4; nt++) {
            int n = bn + wn + nt * 16 + lc;
            float bv = (!Cq && bias) ? bias[n] : 0.f;
#pragma unroll
            for (int r = 0; r < 4; r++) {
                int m = bm + wm + mt * 16 + kq * 4 + r;
                float vr = acc[mt][nt][r];
                if (Cq) {
                    int rows = 1 << vshift;
                    int bb = m >> vshift, rr = m & (rows - 1);
                    if (n < 512) {
                        size_t off = (((size_t)bb * 8 + (n >> 6)) * rows + rr) * 64 + (n & 63);
                        Cq[off] = f2b(vr * sscale);
                        if (Cq2) Cq2[off] = f2b(vr * SCALE_ + qbias2[n]);
                    } else {
                        int nn = n - 512, hh = nn / 96, dv = nn - hh * 96;
                        Cv[(((size_t)bb * 8 + hh) * rows + rr) * 96 + dv] = f2b(vr);
                    }
                } else {
                    float v = vr + bv;
                    if (relu) v = fmaxf(v, 0.f);
                    size_t off = (size_t)m * N + n;
                    if (res) v += ldf(res + off);
                    stf(C + off, v);
                }
            }
        }
    }
}

// Dual-problem launch: blocks [0, a.nwg) run problem a, rest run problem b.
// Keeps small (y-side) GEMMs occupancy-fed by their big x-side sibling.
struct GP {
    const void* Av; const bf16* BwT; void* C;
    int M, N, K;
    const float* bias; int relu; const void* res;
    bf16 *Cq, *Cv, *Cq2; const float* qbias2;
    float sscale; int vshift; int nbx, nwg;
};

template <int AMA, int AMB, typename TC, typename TR>
__global__ __launch_bounds__(256, 4) void dual128_kernel(GP a, GP b)
{
    __shared__ __align__(16) unsigned short As[128 * 64];
    __shared__ __align__(16) unsigned short Bs[128 * 64];
    int tid = threadIdx.x;
    int bid = blockIdx.x;
    if (bid < a.nwg) {
        int sbid = (a.nwg & 7) ? bid : ((bid & 7) * (a.nwg >> 3) + (bid >> 3));
        gemm128_body<AMA, TC, TR>(As, Bs, tid, a.Av, a.BwT, (TC*)a.C,
            a.M, a.N, a.K, a.bias, a.relu, (const TR*)a.res,
            a.Cq, a.Cv, a.Cq2, a.qbias2, a.sscale, a.vshift,
            (sbid / a.nbx) * 128, (sbid % a.nbx) * 128);
    } else {
        int lb = bid - a.nwg;
        int sbid = (b.nwg & 7) ? lb : ((lb & 7) * (b.nwg >> 3) + (lb >> 3));
        gemm128_body<AMB, TC, TR>(As, Bs, tid, b.Av, b.BwT, (TC*)b.C,
            b.M, b.N, b.K, b.bias, b.relu, (const TR*)b.res,
            b.Cq, b.Cv, b.Cq2, b.qbias2, b.sscale, b.vshift,
            (sbid / b.nbx) * 128, (sbid % b.nbx) * 128);
    }
}

// ---------------------------------------------------------------------------
// MFMA bf16 GEMM, 64x64 tile, BK=32, padded LDS, reg-staged (round-3 known-
// good for small/odd problems). AM: 0 = bf16 A (guarded), 1 = fp32 A.
// ---------------------------------------------------------------------------
template <int AM, typename TC>
__global__ __launch_bounds__(256) void mgemm64_kernel(
    const void* __restrict__ Av, const bf16* __restrict__ BwT,
    TC* __restrict__ C, int M, int N, int K)
{
    __shared__ unsigned short As[64][40];
    __shared__ unsigned short Bs[64][40];
    int tid = threadIdx.x, wave = tid >> 6, lane = tid & 63;
    int bm = blockIdx.y * 64, bn = blockIdx.x * 64;
    f32x4 acc[4] = {};
    int am = tid >> 2, ak = (tid & 3) * 8;
    int bn_ = tid & 63, bk = (tid >> 6) * 8;
    const unsigned short* bwt = (const unsigned short*)BwT;

    for (int k0 = 0; k0 < K; k0 += 32) {
        if (AM == 0) {
            s16x8 va = {};
            if (bm + am < M)
                va = *reinterpret_cast<const s16x8*>(
                    (const unsigned short*)Av + (size_t)(bm + am) * K + k0 + ak);
            *reinterpret_cast<s16x8*>(&As[am][ak]) = va;
        } else {
            const float* ap = (const float*)Av + (size_t)(bm + am) * K + k0 + ak;
#pragma unroll
            for (int j = 0; j < 8; j++)
                As[am][ak + j] = (bm + am < M) ? f2bu(ap[j]) : (unsigned short)0;
        }
        *reinterpret_cast<s16x8*>(&Bs[bn_][bk]) =
            *reinterpret_cast<const s16x8*>(bwt + (size_t)(bn + bn_) * K + k0 + bk);
        __syncthreads();

        s16x8 afrag = *reinterpret_cast<const s16x8*>(&As[wave * 16 + (lane & 15)][(lane >> 4) * 8]);
#pragma unroll
        for (int ns = 0; ns < 4; ns++) {
            s16x8 bfrag = *reinterpret_cast<const s16x8*>(&Bs[ns * 16 + (lane & 15)][(lane >> 4) * 8]);
            acc[ns] = MFMA16(afrag, bfrag, acc[ns]);
        }
        __syncthreads();
    }

    int col = lane & 15, rg = (lane >> 4) * 4;
#pragma unroll
    for (int ns = 0; ns < 4; ns++) {
        int n = bn + ns * 16 + col;
#pragma unroll
        for (int r = 0; r < 4; r++) {
            int m = bm + wave * 16 + rg + r;
            if (m >= M) continue;
            stf(C + (size_t)m * N + n, acc[ns][r]);
        }
    }
}

// ---------------------------------------------------------------------------
// Enformer positional features: pos[4095, 96] bf16.
// ---------------------------------------------------------------------------
__global__ __launch_bounds__(64) void pos_kernel(bf16* __restrict__ pos)
{
    int m = blockIdx.x * 64 + threadIdx.x;
    if (m >= NPOS_) return;
    float dist = (float)(m - 2047);
    float ad = fabsf(dist);
    float sgn = (dist > 0.f) ? 1.f : ((dist < 0.f) ? -1.f : 0.f);
    float f[48];
#pragma unroll
    for (int t = 0; t < 16; t++) {
        float hl = exp2f(3.f + (8.f / 15.f) * (float)t);
        f[t] = expf(-0.69314718056f / hl * ad);
    }
#pragma unroll
    for (int t = 0; t < 16; t++) {
        float cw = exp2f((float)(t + 1)) - 1.f;
        f[16 + t] = (cw > ad) ? 1.f : 0.f;
    }
    float pr[16];
    float mx = 0.f;
    if (ad < 0.5f) {
#pragma unroll
        for (int t = 0; t < 16; t++) pr[t] = 1e-8f;
        mx = 1e-8f;
    } else {
        float lad = logf(ad);
#pragma unroll
        for (int t = 0; t < 16; t++) {
            float mean = 128.f * (float)(t + 1);
            float cc = (mean / 64.f) * (mean / 64.f);
            float rate = mean * (1.f / 4096.f);
            float logp = (cc - 1.f) * lad - rate * ad - (lgammaf(cc) - cc * logf(rate));
            float p = expf(logp) + 1e-8f;
            pr[t] = p;
            mx = fmaxf(mx, p);
        }
    }
#pragma unroll
    for (int t = 0; t < 16; t++) f[32 + t] = pr[t] / mx;

    bf16* o = pos + (size_t)m * 96;
#pragma unroll
    for (int c = 0; c < 48; c++) { o[c] = f2b(f[c]); o[48 + c] = f2b(sgn * f[c]); }
}

// ---------------------------------------------------------------------------
// Shifted rel precompute: Tsh[bh][j][i] = dot(kbb[bh,j,:], relq[i-j+511,:]),
// i in [base, base+plen), row pitch plen. Block: 64 j x 256 m super-tile;
// diagonal assembled in LDS (i-space), stored as aligned contiguous chunks.
// ---------------------------------------------------------------------------
#define TP_ 344
__global__ __launch_bounds__(256) void tshift_kernel(
    const bf16* __restrict__ kbb, const bf16* __restrict__ relq,
    bf16* __restrict__ tsh, int base, int plen)
{
    int mc = blockIdx.x, jt = blockIdx.y, bh = blockIdx.z;
    int mbase = mc << 8, jg0 = jt << 6, h = bh & 7;
    int iwin0 = mbase + jg0 - 511 - base;   // global i of (j=jg0, m=mbase)
    if (iwin0 + 318 < 0 || iwin0 >= plen) return;
    int a0 = iwin0 & 7;
    int iwa = iwin0 - a0;                   // aligned global i of LDS col 0
    __shared__ unsigned short Tl[64][TP_];
    int tid = threadIdx.x, wave = tid >> 6, lane = tid & 63;
    int lc = lane & 15, kq = lane >> 4;

    const bf16* ap = kbb + ((size_t)bh * N2_ + jg0 + wave * 16 + lc) * 64 + kq * 8;
    s16x8 af0 = *reinterpret_cast<const s16x8*>(ap);
    s16x8 af1 = *reinterpret_cast<const s16x8*>(ap + 32);

    int jrow = wave * 16 + kq * 4;          // + r = local j row
#pragma unroll
    for (int sub = 0; sub < 2; sub++) {
        int m0 = mbase + sub * 128;
        f32x4 tacc[8] = {};
#pragma unroll
        for (int ns = 0; ns < 8; ns++) {
            const bf16* rp = relq + (size_t)(m0 + ns * 16 + lc) * 512 + h * 64 + kq * 8;
            s16x8 rf0 = *reinterpret_cast<const s16x8*>(rp);
            s16x8 rf1 = *reinterpret_cast<const s16x8*>(rp + 32);
            tacc[ns] = MFMA16(af0, rf0, tacc[ns]);
            tacc[ns] = MFMA16(af1, rf1, tacc[ns]);
        }
#pragma unroll
        for (int ns = 0; ns < 8; ns++)
#pragma unroll
            for (int r = 0; r < 4; r++) {
                int col = sub * 128 + ns * 16 + lc + jrow + r + a0;  // <= 325
                Tl[jrow + r][col] = f2bu(tacc[ns][r]);
            }
    }
    __syncthreads();

    int row = tid >> 2, q = tid & 3;
    int cstart = row + a0;                  // valid cols: [cstart, cstart+256)
    bf16* out = tsh + ((size_t)bh * N2_ + jg0 + row) * (size_t)plen;
#pragma unroll
    for (int s = 0; s < 11; s++) {
        int c = (q + s * 4) * 8;            // 8-elem chunk, 16B aligned
        int i = iwa + c;
        if (c >= cstart && c + 8 <= cstart + 256 && i >= 0 && i + 8 <= plen) {
            *reinterpret_cast<s16x8*>(out + i) =
                *reinterpret_cast<const s16x8*>(&Tl[row][c]);
        } else {
#pragma unroll
            for (int e = 0; e < 8; e++) {
                int ce = c + e, ie = i + e;
                if (ce >= cstart && ce < cstart + 256 && ie >= 0 && ie < plen)
                    out[ie] = *reinterpret_cast<const bf16*>(&Tl[row][ce]);
            }
        }
    }
}

// ---------------------------------------------------------------------------
// MFMA attention pass 1: per 64 q-rows, flash over j. rel term streamed from
// precomputed Tsh (coalesced 64x64 tile stage). Head-major q/k/v.
// ---------------------------------------------------------------------------
__global__ __launch_bounds__(256) void attn1_kernel(
    const bf16* __restrict__ qb, const bf16* __restrict__ kb,
    const bf16* __restrict__ tsh, const bf16* __restrict__ v2,
    bf16* __restrict__ out1, float* __restrict__ mst, float* __restrict__ lst,
    int base, int tpitch)
{
    int bh = blockIdx.y;
    int b = bh >> 3, h = bh & 7;
    int i0 = base + blockIdx.x * 64;
    __shared__ __align__(16) unsigned short Ts[64][72];
    __shared__ __align__(16) unsigned short Ps[64][72];
    __shared__ __align__(16) unsigned short Vs[96][72];
    int tid = threadIdx.x, wave = tid >> 6, lane = tid & 63;
    int lc = lane & 15, kq = lane >> 4;
    int ibase = wave * 16 + kq * 4;

    const bf16* qp = qb + ((size_t)bh * N1_ + i0 + wave * 16 + lc) * 64 + kq * 8;
    s16x8 qf0 = *reinterpret_cast<const s16x8*>(qp);
    s16x8 qf1 = *reinterpret_cast<const s16x8*>(qp + 32);

    int trow = tid >> 2, tchunk = tid & 3;
    const unsigned short* tb0 = (const unsigned short*)tsh
        + ((size_t)bh * N2_ + trow) * tpitch + (i0 - base) + tchunk * 16;
    const unsigned short* vb0 = (const unsigned short*)v2
        + ((size_t)bh * N2_ + trow) * 96 + tchunk * 24;

    float m_run[4], l_run[4];
#pragma unroll
    for (int r = 0; r < 4; r++) { m_run[r] = -1e30f; l_run[r] = 0.f; }
    f32x4 oacc[6] = {};

    for (int j0 = 0; j0 < N2_; j0 += 64) {
        __syncthreads();
        {
            const unsigned short* p = tb0 + (size_t)j0 * tpitch;
            *reinterpret_cast<s16x8*>(&Ts[trow][tchunk * 16]) =
                *reinterpret_cast<const s16x8*>(p);
            *reinterpret_cast<s16x8*>(&Ts[trow][tchunk * 16 + 8]) =
                *reinterpret_cast<const s16x8*>(p + 8);
        }
        {
            const unsigned short* p = vb0 + (size_t)j0 * 96;
            s16x8 w0 = *reinterpret_cast<const s16x8*>(p);
            s16x8 w1 = *reinterpret_cast<const s16x8*>(p + 8);
            s16x8 w2 = *reinterpret_cast<const s16x8*>(p + 16);
            int vd = tchunk * 24;
#pragma unroll
            for (int s = 0; s < 8; s++) Vs[vd + s][trow] = (unsigned short)w0[s];
#pragma unroll
            for (int s = 0; s < 8; s++) Vs[vd + 8 + s][trow] = (unsigned short)w1[s];
#pragma unroll
            for (int s = 0; s < 8; s++) Vs[vd + 16 + s][trow] = (unsigned short)w2[s];
        }
        __syncthreads();

        f32x4 cacc[4] = {};
#pragma unroll
        for (int ns = 0; ns < 4; ns++) {
            const bf16* kp = kb + ((size_t)bh * N2_ + j0 + ns * 16 + lc) * 64 + kq * 8;
            s16x8 kf0 = *reinterpret_cast<const s16x8*>(kp);
            s16x8 kf1 = *reinterpret_cast<const s16x8*>(kp + 32);
            cacc[ns] = MFMA16(qf0, kf0, cacc[ns]);
            cacc[ns] = MFMA16(qf1, kf1, cacc[ns]);
        }
        float Lv[4][4];
#pragma unroll
        for (int ns = 0; ns < 4; ns++) {
            int jloc = ns * 16 + lc;
            s16x4 tv = *reinterpret_cast<const s16x4*>(&Ts[jloc][ibase]);
#pragma unroll
            for (int r = 0; r < 4; r++)
                Lv[ns][r] = cacc[ns][r] + us2f((unsigned short)tv[r]);
        }
#pragma unroll
        for (int r = 0; r < 4; r++) {
            float v = fmaxf(fmaxf(Lv[0][r], Lv[1][r]), fmaxf(Lv[2][r], Lv[3][r]));
            v = fmaxf(v, __shfl_xor(v, 1));
            v = fmaxf(v, __shfl_xor(v, 2));
            v = fmaxf(v, __shfl_xor(v, 4));
            v = fmaxf(v, __shfl_xor(v, 8));
            float mn = fmaxf(m_run[r], v);
            float alpha = __expf(m_run[r] - mn);
            m_run[r] = mn;
            float s = 0.f;
#pragma unroll
            for (int ns = 0; ns < 4; ns++) {
                float p = __expf(Lv[ns][r] - mn);
                Lv[ns][r] = p;
                s += p;
            }
            s += __shfl_xor(s, 1);
            s += __shfl_xor(s, 2);
            s += __shfl_xor(s, 4);
            s += __shfl_xor(s, 8);
            l_run[r] = l_run[r] * alpha + s;
#pragma unroll
            for (int ns6 = 0; ns6 < 6; ns6++) oacc[ns6][r] *= alpha;
        }
#pragma unroll
        for (int ns = 0; ns < 4; ns++)
#pragma unroll
            for (int r = 0; r < 4; r++)
                Ps[ibase + r][ns * 16 + lc] = f2bu(Lv[ns][r]);
#pragma unroll
        for (int kk = 0; kk < 2; kk++) {
            s16x8 pf = *reinterpret_cast<const s16x8*>(&Ps[wave * 16 + lc][kq * 8 + kk * 32]);
#pragma unroll
            for (int ns6 = 0; ns6 < 6; ns6++) {
                s16x8 vf = *reinterpret_cast<const s16x8*>(&Vs[ns6 * 16 + lc][kq * 8 + kk * 32]);
                oacc[ns6] = MFMA16(pf, vf, oacc[ns6]);
            }
        }
    }

    float invl[4];
#pragma unroll
    for (int r = 0; r < 4; r++) invl[r] = 1.f / l_run[r];
#pragma unroll
    for (int ns6 = 0; ns6 < 6; ns6++)
#pragma unroll
        for (int r = 0; r < 4; r++)
            out1[(size_t)(b * N1_ + i0 + ibase + r) * 768 + h * 96 + ns6 * 16 + lc]
                = f2b(oacc[ns6][r] * invl[r]);
    if (lc == 0) {
#pragma unroll
        for (int r = 0; r < 4; r++) {
            mst[(size_t)bh * N1_ + i0 + ibase + r] = m_run[r];
            lst[(size_t)bh * N1_ + i0 + ibase + r] = l_run[r];
        }
    }
}

// ---------------------------------------------------------------------------
// MFMA attention pass 2: per 64 j-rows x 512-i quarter (blockIdx.z), writes
// quarter partials. rel term from Tsh; head-major q/k/v1.
// ---------------------------------------------------------------------------
__global__ __launch_bounds__(256) void attn2_kernel(
    const bf16* __restrict__ qb, const bf16* __restrict__ kb,
    const bf16* __restrict__ tsh, const bf16* __restrict__ v1,
    bf16* __restrict__ out2b, const float* __restrict__ mst,
    const float* __restrict__ lst, int base, int tpitch)
{
    int jt = blockIdx.x, bh = blockIdx.y;
    int b = bh >> 3, h = bh & 7;
    int ib = base + blockIdx.z * 512;
    bf16* out2 = out2b + (size_t)(ib >> 9) * ((size_t)B_ * N2_ * 768);
    int j0 = jt * 64;
    __shared__ __align__(16) unsigned short Ts[64][72];
    __shared__ __align__(16) unsigned short Ps[64][72];
    __shared__ __align__(16) unsigned short Vs[96][72];
    int tid = threadIdx.x, wave = tid >> 6, lane = tid & 63;
    int lc = lane & 15, kq = lane >> 4;
    int ibase = wave * 16 + kq * 4;

    s16x8 kf0[4], kf1[4];
#pragma unroll
    for (int ns = 0; ns < 4; ns++) {
        const bf16* kp = kb + ((size_t)bh * N2_ + j0 + ns * 16 + lc) * 64 + kq * 8;
        kf0[ns] = *reinterpret_cast<const s16x8*>(kp);
        kf1[ns] = *reinterpret_cast<const s16x8*>(kp + 32);
    }

    int trow = tid >> 2, tchunk = tid & 3;
    const unsigned short* tb0 = (const unsigned short*)tsh
        + ((size_t)bh * N2_ + j0 + trow) * tpitch + tchunk * 16;
    const unsigned short* vb0 = (const unsigned short*)v1
        + ((size_t)bh * N1_ + trow) * 96 + tchunk * 24;

    f32x4 oacc[6] = {};
    for (int i0 = ib; i0 < ib + 512; i0 += 64) {
        __syncthreads();
        {
            const unsigned short* p = tb0 + (i0 - base);
            *reinterpret_cast<s16x8*>(&Ts[trow][tchunk * 16]) =
                *reinterpret_cast<const s16x8*>(p);
            *reinterpret_cast<s16x8*>(&Ts[trow][tchunk * 16 + 8]) =
                *reinterpret_cast<const s16x8*>(p + 8);
        }
        {
            const unsigned short* p = vb0 + (size_t)i0 * 96;
            s16x8 w0 = *reinterpret_cast<const s16x8*>(p);
            s16x8 w1 = *reinterpret_cast<const s16x8*>(p + 8);
            s16x8 w2 = *reinterpret_cast<const s16x8*>(p + 16);
            int vd = tchunk * 24;
#pragma unroll
            for (int s = 0; s < 8; s++) Vs[vd + s][trow] = (unsigned short)w0[s];
#pragma unroll
            for (int s = 0; s < 8; s++) Vs[vd + 8 + s][trow] = (unsigned short)w1[s];
#pragma unroll
            for (int s = 0; s < 8; s++) Vs[vd + 16 + s][trow] = (unsigned short)w2[s];
        }
        __syncthreads();

        const bf16* qp = qb + ((size_t)bh * N1_ + i0 + wave * 16 + lc) * 64 + kq * 8;
        s16x8 qf0 = *reinterpret_cast<const s16x8*>(qp);
        s16x8 qf1 = *reinterpret_cast<const s16x8*>(qp + 32);
        f32x4 cacc[4] = {};
#pragma unroll
        for (int ns = 0; ns < 4; ns++) {
            cacc[ns] = MFMA16(qf0, kf0[ns], cacc[ns]);
            cacc[ns] = MFMA16(qf1, kf1[ns], cacc[ns]);
        }
        float mi[4], invli[4];
#pragma unroll
        for (int r = 0; r < 4; r++) {
            mi[r] = mst[(size_t)bh * N1_ + i0 + ibase + r];
            invli[r] = 1.f / lst[(size_t)bh * N1_ + i0 + ibase + r];
        }
#pragma unroll
        for (int ns = 0; ns < 4; ns++) {
            int jloc = ns * 16 + lc;
            s16x4 tv = *reinterpret_cast<const s16x4*>(&Ts[jloc][ibase]);
            s16x4 pw;
#pragma unroll
            for (int r = 0; r < 4; r++) {
                float L = cacc[ns][r] + us2f((unsigned short)tv[r]);
                pw[r] = (short)f2bu(__expf(L - mi[r]) * invli[r]);
            }
            *reinterpret_cast<s16x4*>(&Ps[jloc][ibase]) = pw;
        }
        __syncthreads();
#pragma unroll
        for (int kk = 0; kk < 2; kk++) {
            s16x8 pf = *reinterpret_cast<const s16x8*>(&Ps[wave * 16 + lc][kq * 8 + kk * 32]);
#pragma unroll
            for (int ns6 = 0; ns6 < 6; ns6++) {
                s16x8 vf = *reinterpret_cast<const s16x8*>(&Vs[ns6 * 16 + lc][kq * 8 + kk * 32]);
                oacc[ns6] = MFMA16(pf, vf, oacc[ns6]);
            }
        }
    }

#pragma unroll
    for (int ns6 = 0; ns6 < 6; ns6++)
#pragma unroll
        for (int r = 0; r < 4; r++)
            out2[(size_t)(b * N2_ + j0 + ibase + r) * 768 + h * 96 + ns6 * 16 + lc]
                = f2b(oacc[ns6][r]);
}

// ---------------------------------------------------------------------------
extern "C" void kernel_launch(void* const* d_in, const int* in_sizes, int n_in,
                              void* d_out, int out_size, void* d_ws, size_t ws_size,
                              hipStream_t stream)
{
    (void)in_sizes; (void)n_in; (void)out_size;
    const float* x      = (const float*)d_in[0];
    const float* y0     = (const float*)d_in[1];
    const float* Wres   = (const float*)d_in[2];
    const float* lnx_g  = (const float*)d_in[3];
    const float* lnx_b  = (const float*)d_in[4];
    const float* lny_g  = (const float*)d_in[5];
    const float* lny_b  = (const float*)d_in[6];
    const float* Wq     = (const float*)d_in[7];
    const float* Wk     = (const float*)d_in[8];
    const float* Wv1    = (const float*)d_in[9];
    const float* Wv2    = (const float*)d_in[10];
    const float* Wo1    = (const float*)d_in[11];
    const float* bo1    = (const float*)d_in[12];
    const float* Wo2    = (const float*)d_in[13];
    const float* bo2    = (const float*)d_in[14];
    const float* Wrel   = (const float*)d_in[15];
    const float* rel_pb = (const float*)d_in[16];
    const float* fx_g   = (const float*)d_in[17];
    const float* fx_b   = (const float*)d_in[18];
    const float* fx_w1  = (const float*)d_in[19];
    const float* fx_b1  = (const float*)d_in[20];
    const float* fx_w2  = (const float*)d_in[21];
    const float* fx_b2  = (const float*)d_in[22];
    const float* fy_g   = (const float*)d_in[23];
    const float* fy_b   = (const float*)d_in[24];
    const float* fy_w1  = (const float*)d_in[25];
    const float* fy_b1  = (const float*)d_in[26];
    const float* fy_w2  = (const float*)d_in[27];
    const float* fy_b2  = (const float*)d_in[28];

    float* out_x = (float*)d_out;                          // [4,2048,768] fp32
    float* out_y = out_x + (size_t)B_ * N1_ * D_;          // [4,512,768] fp32
    bf16* out1 = (bf16*)d_out;  // attn out1 parked in d_out (dies before fp32 writes)

    // ---- workspace ----
    char* W = (char*)d_ws;
    size_t o = 0;
    auto alloc = [&](size_t bytes) { char* p = W + o; o += (bytes + 255) & ~(size_t)255; return p; };
    bf16*   qb   = (bf16*)alloc((size_t)B_ * N1_ * 512 * 2);   // head-major [bh][2048][64]
    bf16*   kb   = (bf16*)alloc((size_t)B_ * N2_ * 512 * 2);   // [bh][512][64]
    bf16*   posb = (bf16*)alloc((size_t)NPOS_ * 96 * 2);
    bf16*   relq = (bf16*)alloc((size_t)NPOS_ * 512 * 2);
    bf16*   v1b  = (bf16*)alloc((size_t)B_ * N1_ * 768 * 2);   // [bh][2048][96]
    bf16*   hx2  = (bf16*)alloc((size_t)B_ * N1_ * 768 * 2);   // 4x out2 quarter slabs / hx
    bf16*   v2b  = (bf16*)alloc((size_t)B_ * N2_ * 768 * 2);   // [bh][512][96]
    float*  yb   = (float*)alloc((size_t)B_ * N2_ * 768 * 4);  // fp32 residual; later hy
    bf16*   kbbb = (bf16*)alloc((size_t)B_ * N2_ * 512 * 2);   // [bh][512][64]
    bf16*   wpool= (bf16*)alloc((size_t)9093120 * 2);          // W^T packed
    float*  mst  = (float*)alloc((size_t)B_ * H_ * N1_ * 4);
    float*  lst  = (float*)alloc((size_t)B_ * H_ * N1_ * 4);

    // Tsh / x1 / y1 time-share the tail region (x1,y1 dead during attention).
    size_t x1y1 = ((size_t)B_ * N1_ * 768 + (size_t)B_ * N2_ * 768) * 2;  // 15.73 MB
    size_t rem = ws_size > o ? ws_size - o : 0;
    int plen = 512;
    if (rem >= (size_t)32 * 512 * 2048 * 2 + 1024) plen = 2048;
    else if (rem >= (size_t)32 * 512 * 1024 * 2 + 1024) plen = 1024;
    size_t tshB = (size_t)32 * 512 * (size_t)plen * 2;
    bf16* tshb = (bf16*)alloc(tshB > x1y1 ? tshB : x1y1);
    bf16* x1 = tshb;
    bf16* y1 = x1 + (size_t)B_ * N1_ * 768;

    bf16* x4 = qb;            // after attention, qb..relq span is dead
    bf16* y4 = v2b;
    bf16* hx = v1b;           // FFNx hidden spans v1b+hx2
    bf16* out2h = hx2;        // 4 quarter slabs (3.15MB each) inside hx2
    bf16* hy = (bf16*)yb;     // FFNy hidden: yb dead after O1|O2 (res read)
    bf16* x4ln = x1;          // Tsh dead by step 7
    bf16* y4ln = y1;

    // packed W^T offsets (elements)
    const unsigned OW_RES = 0, OW_QV1 = 1179648, OW_KV2 = 2162688, OW_O1 = 3145728,
                   OW_O2 = 3735552, OW_REL = 4325376, OW_FXW1 = 4374528,
                   OW_FXW2 = 5554176, OW_FYW1 = 6733824, OW_FYW2 = 7913472;

    PackT pa;
    const float* srcs[12] = {Wres, Wq, Wv1, Wk, Wv2, Wo1, Wo2, Wrel,
                             fx_w1, fx_w2, fy_w1, fy_w2};
    unsigned Ks[12] = {1536, 768, 768, 768, 768, 768, 768, 96, 768, 1536, 768, 1536};
    unsigned Nss[12] = {768, 512, 768, 512, 768, 768, 768, 512, 1536, 768, 1536, 768};
    unsigned dbs[12] = {OW_RES, OW_QV1, OW_QV1 + 393216, OW_KV2, OW_KV2 + 393216,
                        OW_O1, OW_O2, OW_REL, OW_FXW1, OW_FXW2, OW_FYW1, OW_FYW2};
    unsigned drs[12] = {1536, 768, 768, 768, 768, 768, 768, 96, 768, 1536, 768, 1536};
    unsigned cum = 0;
    for (int i = 0; i < 12; i++) {
        pa.src[i] = srcs[i]; pa.K[i] = Ks[i]; pa.N[i] = Nss[i];
        pa.dbase[i] = dbs[i]; pa.drow[i] = drs[i];
        pa.t0[i] = cum;
        cum += (Ks[i] >> 5) * (Nss[i] >> 6);
    }
    pa.t0[12] = cum;

    dim3 blk(256);
    // 0. transpose-pack weights
    packT_kernel<<<cum, blk, 0, stream>>>(pa, wpool);
    // 1. y = y0 @ W_res (fp32 A, fp32 out; 384-block 64-tile — occupancy path)
    mgemm64_kernel<1, float><<<dim3(12, 32), blk, 0, stream>>>(
        y0, wpool + OW_RES, yb, B_ * N2_, D_, 1536);
    // 2. LayerNorms materialized as bf16
    lnfull_kernel<float><<<B_ * N1_, 64, 0, stream>>>(x, lnx_g, lnx_b, x1);
    lnfull_kernel<float><<<B_ * N2_, 64, 0, stream>>>(yb, lny_g, lny_b, y1);
    // 3. fused projections: QV1 (x-side) paired with KV2 (y-side)
    {
        GP a{x1, wpool + OW_QV1, nullptr, B_ * N1_, 1280, D_,
             nullptr, 0, nullptr, qb, v1b, nullptr, nullptr, SCALE_, 11, 10, 640};
        GP b{y1, wpool + OW_KV2, nullptr, B_ * N2_, 1280, D_,
             nullptr, 0, nullptr, kb, v2b, kbbb, rel_pb, 1.f, 9, 10, 160};
        dual128_kernel<0, 0, bf16, float><<<800, blk, 0, stream>>>(a, b);
    }
    // 4. positional features + rel_q
    pos_kernel<<<(NPOS_ + 63) / 64, 64, 0, stream>>>(posb);
    mgemm64_kernel<0, bf16><<<dim3(8, 64), blk, 0, stream>>>(
        posb, wpool + OW_REL, relq, NPOS_, 512, 96);
    // 5. shifted-rel precompute + attention, phased to fit workspace
    for (int base = 0; base < N1_; base += plen) {
        tshift_kernel<<<dim3(10, 8, 32), blk, 0, stream>>>(kbbb, relq, tshb, base, plen);
        attn1_kernel<<<dim3(plen / 64, 32), blk, 0, stream>>>(
            qb, kb, tshb, v2b, out1, mst, lst, base, plen);
        attn2_kernel<<<dim3(8, 32, plen / 512), blk, 0, stream>>>(
            qb, kb, tshb, v1b, out2h, mst, lst, base, plen);
    }
    // 6. output projections + residuals: O1 paired with O2 (4-slab sum)
    {
        GP a{out1, wpool + OW_O1, x4, B_ * N1_, D_, D_,
             bo1, 0, x, nullptr, nullptr, nullptr, nullptr, 0.f, 0, 6, 384};
        GP b{out2h, wpool + OW_O2, y4, B_ * N2_, D_, D_,
             bo2, 0, yb, nullptr, nullptr, nullptr, nullptr, 0.f, 0, 6, 96};
        dual128_kernel<0, 2, bf16, float><<<480, blk, 0, stream>>>(a, b);
    }
    // 7. FFN LayerNorms
    lnfull_kernel<bf16><<<B_ * N1_, 64, 0, stream>>>(x4, fx_g, fx_b, x4ln);
    lnfull_kernel<bf16><<<B_ * N2_, 64, 0, stream>>>(y4, fy_g, fy_b, y4ln);
    // 8. FFN W1: FXW1 paired with FYW1 (hy in dead yb region)
    {
        GP a{x4ln, wpool + OW_FXW1, hx, B_ * N1_, 1536, D_,
             fx_b1, 1, nullptr, nullptr, nullptr, nullptr, nullptr, 0.f, 0, 12, 768};
        GP b{y4ln, wpool + OW_FYW1, hy, B_ * N2_, 1536, D_,
             fy_b1, 1, nullptr, nullptr, nullptr, nullptr, nullptr, 0.f, 0, 12, 192};
        dual128_kernel<0, 0, bf16, float><<<960, blk, 0, stream>>>(a, b);
    }
    // 9. FFN W2: FXW2 paired with FYW2 -> fp32 outputs
    {
        GP a{hx, wpool + OW_FXW2, out_x, B_ * N1_, D_, 1536,
             fx_b2, 0, x4, nullptr, nullptr, nullptr, nullptr, 0.f, 0, 6, 384};
        GP b{hy, wpool + OW_FYW2, out_y, B_ * N2_, D_, 1536,
             fy_b2, 0, y4, nullptr, nullptr, nullptr, nullptr, 0.f, 0, 6, 96};
        dual128_kernel<0, 0, float, bf16><<<480, blk, 0, stream>>>(a, b);
    }
}

// Round 6
// 556.405 us; speedup vs baseline: 1.5293x; 1.0790x over previous
//
#include <hip/hip_runtime.h>
#include <hip/hip_bf16.h>
#include <math.h>

typedef __hip_bfloat16 bf16;
typedef short s16x8 __attribute__((ext_vector_type(8)));
typedef short s16x4 __attribute__((ext_vector_type(4)));
typedef float f32x4 __attribute__((ext_vector_type(4)));

#define B_    4
#define N1_   2048
#define N2_   512
#define D_    768
#define H_    8
#define DK_   64
#define DV_   96
#define NPOS_ 4095
#define SCALE_ 0.125f

__device__ __forceinline__ float b2f(bf16 v) { return __bfloat162float(v); }
__device__ __forceinline__ bf16  f2b(float v) { return __float2bfloat16(v); }
__device__ __forceinline__ float us2f(unsigned short u) {
    return __uint_as_float(((unsigned int)u) << 16);
}
__device__ __forceinline__ unsigned short f2bu(float v) {
    bf16 t = __float2bfloat16(v);
    return *reinterpret_cast<unsigned short*>(&t);
}
__device__ __forceinline__ float ldf(const float* p) { return *p; }
__device__ __forceinline__ float ldf(const bf16* p)  { return __bfloat162float(*p); }
__device__ __forceinline__ void stf(float* p, float v) { *p = v; }
__device__ __forceinline__ void stf(bf16* p, float v)  { *p = f2b(v); }
#define MFMA16(a, b, c) __builtin_amdgcn_mfma_f32_16x16x32_bf16((a), (b), (c), 0, 0, 0)

// Async global->LDS, 16B per lane. LDS dest is wave-uniform base + lane*16.
__device__ __forceinline__ void gl16(const unsigned short* g, unsigned short* l) {
    __builtin_amdgcn_global_load_lds(
        (const __attribute__((address_space(1))) unsigned int*)g,
        (__attribute__((address_space(3))) unsigned int*)l, 16, 0, 0);
}

// ---------------------------------------------------------------------------
// Transpose-pack: W[K][N] fp32 -> W^T[n][k] bf16 at dst+dbase, row stride drow.
// ---------------------------------------------------------------------------
struct PackT {
    const float* src[12];
    unsigned K[12], N[12], dbase[12], drow[12];
    unsigned t0[13];
};

__global__ __launch_bounds__(256) void packT_kernel(PackT pa, bf16* __restrict__ dst)
{
    int bid = blockIdx.x, s = 0;
    while (s < 11 && bid >= (int)pa.t0[s + 1]) s++;
    int t = bid - (int)pa.t0[s];
    unsigned K = pa.K[s], N = pa.N[s];
    unsigned ntk = K >> 5;
    unsigned k0 = (t % ntk) << 5, n0 = (t / ntk) << 6;
    __shared__ float tile[32][65];
    const float* src = pa.src[s];
    int tid = threadIdx.x;
    {
        int e = tid * 8, k = e >> 6, n = e & 63;
        const float* p = src + (size_t)(k0 + k) * N + n0 + n;
#pragma unroll
        for (int j = 0; j < 8; j++) tile[k][n + j] = p[j];
    }
    __syncthreads();
    {
        int f = tid * 8, n = f >> 5, k = f & 31;
        bf16* q = dst + (size_t)pa.dbase[s] + (size_t)(n0 + n) * pa.drow[s] + k0 + k;
#pragma unroll
        for (int j = 0; j < 8; j++) q[j] = f2b(tile[k + j][n]);
    }
}

// ---------------------------------------------------------------------------
// fp32 -> bf16 elementwise convert, 8 per thread.
// ---------------------------------------------------------------------------
__global__ __launch_bounds__(256) void cvt8_kernel(
    const float* __restrict__ in, bf16* __restrict__ out)
{
    int i = (blockIdx.x * 256 + threadIdx.x) * 8;
    f32x4 a = *reinterpret_cast<const f32x4*>(in + i);
    f32x4 b = *reinterpret_cast<const f32x4*>(in + i + 4);
    s16x8 w;
#pragma unroll
    for (int j = 0; j < 4; j++) {
        w[j] = (short)f2bu(a[j]);
        w[4 + j] = (short)f2bu(b[j]);
    }
    *reinterpret_cast<s16x8*>((unsigned short*)out + i) = w;
}

// ---------------------------------------------------------------------------
// Full LayerNorm over D_=768 -> bf16 out. One wave per row.
// ---------------------------------------------------------------------------
template <typename T>
__global__ __launch_bounds__(64) void lnfull_kernel(
    const T* __restrict__ in, const float* __restrict__ g,
    const float* __restrict__ b, bf16* __restrict__ out)
{
    int row = blockIdx.x, lane = threadIdx.x;
    const T* p = in + (size_t)row * D_;
    float v[12];
    float s = 0.f;
#pragma unroll
    for (int i = 0; i < 12; i++) { v[i] = ldf(p + lane + i * 64); s += v[i]; }
#pragma unroll
    for (int o = 32; o > 0; o >>= 1) s += __shfl_down(s, o);
    float mean = __shfl(s, 0) * (1.f / 768.f);
    float var = 0.f;
#pragma unroll
    for (int i = 0; i < 12; i++) { float d = v[i] - mean; var += d * d; }
#pragma unroll
    for (int o = 32; o > 0; o >>= 1) var += __shfl_down(var, o);
    float rstd = rsqrtf(__shfl(var, 0) * (1.f / 768.f) + 1e-5f);
    bf16* q = out + (size_t)row * D_;
#pragma unroll
    for (int i = 0; i < 12; i++) {
        int c = lane + i * 64;
        q[c] = f2b((v[i] - mean) * rstd * g[c] + b[c]);
    }
}

// ---------------------------------------------------------------------------
// W_res split-K (K=1536 -> 4 x 384), 128x128 tile, bf16 A via gl16.
// Writes 4 fp32 partial slabs Cp[s][2048][768]. Grid = 384 linear.
// ---------------------------------------------------------------------------
__global__ __launch_bounds__(256, 4) void wres_splitk_kernel(
    const bf16* __restrict__ Av, const bf16* __restrict__ BwT,
    float* __restrict__ Cp)
{
    __shared__ __align__(16) unsigned short As[128 * 64];
    __shared__ __align__(16) unsigned short Bs[128 * 64];
    const int K = 1536;
    int tid = threadIdx.x, wave = tid >> 6, lane = tid & 63;
    int lc = lane & 15, kq = lane >> 4;
    int wm = (wave & 1) * 64, wn = (wave >> 1) * 64;
    int bid = blockIdx.x;
    int sbid = (bid & 7) * 48 + (bid >> 3);   // 384 = 8 * 48, bijective
    int s = sbid / 96, t = sbid % 96;         // 4 splits x (16 x 6)
    int bm = (t / 6) * 128, bn = (t % 6) * 128;
    int ks = s * 384;
    f32x4 acc[4][4] = {};
    int grow = tid >> 3, gcol = (tid & 7) * 8;
    const unsigned short* ag = (const unsigned short*)Av + (size_t)(bm + grow) * K + gcol;
    const unsigned short* bg = (const unsigned short*)BwT + (size_t)(bn + grow) * K + gcol;
    unsigned short* asl = As + wave * 512;
    unsigned short* bsl = Bs + wave * 512;

    for (int k0 = ks; k0 < ks + 384; k0 += 64) {
#pragma unroll
        for (int it = 0; it < 4; it++) {
            gl16(ag + (size_t)(it * 32) * K + k0, asl + it * 2048);
            gl16(bg + (size_t)(it * 32) * K + k0, bsl + it * 2048);
        }
        __syncthreads();
#pragma unroll
        for (int kh = 0; kh < 2; kh++) {
            s16x8 af[4], bf[4];
#pragma unroll
            for (int mt = 0; mt < 4; mt++)
                af[mt] = *reinterpret_cast<const s16x8*>(&As[(wm + mt * 16 + lc) * 64 + kh * 32 + kq * 8]);
#pragma unroll
            for (int nt = 0; nt < 4; nt++)
                bf[nt] = *reinterpret_cast<const s16x8*>(&Bs[(wn + nt * 16 + lc) * 64 + kh * 32 + kq * 8]);
#pragma unroll
            for (int mt = 0; mt < 4; mt++)
#pragma unroll
                for (int nt = 0; nt < 4; nt++)
                    acc[mt][nt] = MFMA16(af[mt], bf[nt], acc[mt][nt]);
        }
        __syncthreads();
    }

    float* out = Cp + (size_t)s * (2048 * 768);
#pragma unroll
    for (int mt = 0; mt < 4; mt++)
#pragma unroll
        for (int nt = 0; nt < 4; nt++) {
            int n = bn + wn + nt * 16 + lc;
#pragma unroll
            for (int r = 0; r < 4; r++) {
                int m = bm + wm + mt * 16 + kq * 4 + r;
                out[(size_t)m * 768 + n] = acc[mt][nt][r];
            }
        }
}

// ---------------------------------------------------------------------------
// Reduce 4 split-K slabs + LayerNorm fused: writes yb fp32 and y1 bf16.
// One wave per row.
// ---------------------------------------------------------------------------
__global__ __launch_bounds__(64) void lnred4_kernel(
    const float* __restrict__ Cp, const float* __restrict__ g,
    const float* __restrict__ b, float* __restrict__ yb, bf16* __restrict__ y1)
{
    int row = blockIdx.x, lane = threadIdx.x;
    const size_t SL = (size_t)2048 * 768;
    const float* p = Cp + (size_t)row * 768;
    float* yo = yb + (size_t)row * 768;
    float v[12];
    float s = 0.f;
#pragma unroll
    for (int i = 0; i < 12; i++) {
        int c = lane + i * 64;
        float t = p[c] + p[SL + c] + p[2 * SL + c] + p[3 * SL + c];
        v[i] = t; s += t;
        yo[c] = t;
    }
#pragma unroll
    for (int o = 32; o > 0; o >>= 1) s += __shfl_down(s, o);
    float mean = __shfl(s, 0) * (1.f / 768.f);
    float var = 0.f;
#pragma unroll
    for (int i = 0; i < 12; i++) { float d = v[i] - mean; var += d * d; }
#pragma unroll
    for (int o = 32; o > 0; o >>= 1) var += __shfl_down(var, o);
    float rstd = rsqrtf(__shfl(var, 0) * (1.f / 768.f) + 1e-5f);
    bf16* q = y1 + (size_t)row * D_;
#pragma unroll
    for (int i = 0; i < 12; i++) {
        int c = lane + i * 64;
        q[c] = f2b((v[i] - mean) * rstd * g[c] + b[c]);
    }
}

// ---------------------------------------------------------------------------
// 128x128 GEMM body (m97 structure), called by the dual-problem kernels.
// AM: 0 = bf16 A via global_load_lds; 2 = bf16 A summed over 4 slabs.
// ---------------------------------------------------------------------------
template <int AM, typename TC, typename TR>
__device__ __forceinline__ void gemm128_body(
    unsigned short* As, unsigned short* Bs, int tid,
    const void* Av, const bf16* BwT, TC* C, int M, int N, int K,
    const float* bias, int relu, const TR* res,
    bf16* Cq, bf16* Cv, bf16* Cq2, const float* qbias2,
    float sscale, int vshift, int bm, int bn)
{
    int wave = tid >> 6, lane = tid & 63;
    int lc = lane & 15, kq = lane >> 4;
    int wm = (wave & 1) * 64, wn = (wave >> 1) * 64;
    f32x4 acc[4][4] = {};
    int grow = tid >> 3, gcol = (tid & 7) * 8;
    const unsigned short* bg = (const unsigned short*)BwT + (size_t)(bn + grow) * K + gcol;
    unsigned short* asl = As + wave * 512;
    unsigned short* bsl = Bs + wave * 512;
    const size_t SL = (size_t)B_ * N2_ * 768;

    for (int k0 = 0; k0 < K; k0 += 64) {
        if (AM == 0) {
            const unsigned short* ag = (const unsigned short*)Av + (size_t)(bm + grow) * K + k0 + gcol;
#pragma unroll
            for (int it = 0; it < 4; it++)
                gl16(ag + (size_t)(it * 32) * K, asl + it * 2048);
        } else {
#pragma unroll
            for (int it = 0; it < 4; it++) {
                const unsigned short* a0 = (const unsigned short*)Av
                    + (size_t)(bm + grow + it * 32) * K + k0 + gcol;
                s16x8 v0 = *reinterpret_cast<const s16x8*>(a0);
                s16x8 v1 = *reinterpret_cast<const s16x8*>(a0 + SL);
                s16x8 v2 = *reinterpret_cast<const s16x8*>(a0 + 2 * SL);
                s16x8 v3 = *reinterpret_cast<const s16x8*>(a0 + 3 * SL);
                s16x8 w;
#pragma unroll
                for (int j = 0; j < 8; j++)
                    w[j] = (short)f2bu(us2f((unsigned short)v0[j]) + us2f((unsigned short)v1[j]) +
                                       us2f((unsigned short)v2[j]) + us2f((unsigned short)v3[j]));
                *reinterpret_cast<s16x8*>(&As[(grow + it * 32) * 64 + gcol]) = w;
            }
        }
#pragma unroll
        for (int it = 0; it < 4; it++)
            gl16(bg + (size_t)(it * 32) * K + k0, bsl + it * 2048);
        __syncthreads();
#pragma unroll
        for (int kh = 0; kh < 2; kh++) {
            s16x8 af[4], bf[4];
#pragma unroll
            for (int mt = 0; mt < 4; mt++)
                af[mt] = *reinterpret_cast<const s16x8*>(&As[(wm + mt * 16 + lc) * 64 + kh * 32 + kq * 8]);
#pragma unroll
            for (int nt = 0; nt < 4; nt++)
                bf[nt] = *reinterpret_cast<const s16x8*>(&Bs[(wn + nt * 16 + lc) * 64 + kh * 32 + kq * 8]);
#pragma unroll
            for (int mt = 0; mt < 4; mt++)
#pragma unroll
                for (int nt = 0; nt < 4; nt++)
                    acc[mt][nt] = MFMA16(af[mt], bf[nt], acc[mt][nt]);
        }
        __syncthreads();
    }

#pragma unroll
    for (int mt = 0; mt < 4; mt++) {
#pragma unroll
        for (int nt = 0; nt < 4; nt++) {
            int n = bn + wn + nt * 16 + lc;
            float bv = (!Cq && bias) ? bias[n] : 0.f;
#pragma unroll
            for (int r = 0; r < 4; r++) {
                int m = bm + wm + mt * 16 + kq * 4 + r;
                float vr = acc[mt][nt][r];
                if (Cq) {
                    int rows = 1 << vshift;
                    int bb = m >> vshift, rr = m & (rows - 1);
                    if (n < 512) {
                        size_t off = (((size_t)bb * 8 + (n >> 6)) * rows + rr) * 64 + (n & 63);
                        Cq[off] = f2b(vr * sscale);
                        if (Cq2) Cq2[off] = f2b(vr * SCALE_ + qbias2[n]);
                    } else {
                        int nn = n - 512, hh = nn / 96, dv = nn - hh * 96;
                        Cv[(((size_t)bb * 8 + hh) * rows + rr) * 96 + dv] = f2b(vr);
                    }
                } else {
                    float v = vr + bv;
                    if (relu) v = fmaxf(v, 0.f);
                    size_t off = (size_t)m * N + n;
                    if (res) v += ldf(res + off);
                    stf(C + off, v);
                }
            }
        }
    }
}

// Dual-problem launch: blocks [0, a.nwg) run problem a, rest run problem b.
struct GP {
    const void* Av; const bf16* BwT; void* C;
    int M, N, K;
    const float* bias; int relu; const void* res;
    bf16 *Cq, *Cv, *Cq2; const float* qbias2;
    float sscale; int vshift; int nbx, nwg;
};

template <int AMA, int AMB, typename TC, typename TR>
__global__ __launch_bounds__(256, 4) void dual128_kernel(GP a, GP b)
{
    __shared__ __align__(16) unsigned short As[128 * 64];
    __shared__ __align__(16) unsigned short Bs[128 * 64];
    int tid = threadIdx.x;
    int bid = blockIdx.x;
    if (bid < a.nwg) {
        int sbid = (a.nwg & 7) ? bid : ((bid & 7) * (a.nwg >> 3) + (bid >> 3));
        gemm128_body<AMA, TC, TR>(As, Bs, tid, a.Av, a.BwT, (TC*)a.C,
            a.M, a.N, a.K, a.bias, a.relu, (const TR*)a.res,
            a.Cq, a.Cv, a.Cq2, a.qbias2, a.sscale, a.vshift,
            (sbid / a.nbx) * 128, (sbid % a.nbx) * 128);
    } else {
        int lb = bid - a.nwg;
        int sbid = (b.nwg & 7) ? lb : ((lb & 7) * (b.nwg >> 3) + (lb >> 3));
        gemm128_body<AMB, TC, TR>(As, Bs, tid, b.Av, b.BwT, (TC*)b.C,
            b.M, b.N, b.K, b.bias, b.relu, (const TR*)b.res,
            b.Cq, b.Cv, b.Cq2, b.qbias2, b.sscale, b.vshift,
            (sbid / b.nbx) * 128, (sbid % b.nbx) * 128);
    }
}

// Triple launch: QV1 (128^2) + KV2 (128^2) + REL (64^2, M=4095, K=96).
__global__ __launch_bounds__(256, 4) void dual3_kernel(GP a, GP b,
    const bf16* __restrict__ relA, const bf16* __restrict__ relB,
    bf16* __restrict__ relC)
{
    __shared__ __align__(16) unsigned short As[128 * 64];
    __shared__ __align__(16) unsigned short Bs[128 * 64];
    int tid = threadIdx.x;
    int bid = blockIdx.x;
    if (bid < a.nwg) {
        int sbid = (bid & 7) * (a.nwg >> 3) + (bid >> 3);
        gemm128_body<0, bf16, float>(As, Bs, tid, a.Av, a.BwT, (bf16*)a.C,
            a.M, a.N, a.K, a.bias, a.relu, (const float*)a.res,
            a.Cq, a.Cv, a.Cq2, a.qbias2, a.sscale, a.vshift,
            (sbid / a.nbx) * 128, (sbid % a.nbx) * 128);
    } else if (bid < a.nwg + b.nwg) {
        int lb = bid - a.nwg;
        int sbid = (lb & 7) * (b.nwg >> 3) + (lb >> 3);
        gemm128_body<0, bf16, float>(As, Bs, tid, b.Av, b.BwT, (bf16*)b.C,
            b.M, b.N, b.K, b.bias, b.relu, (const float*)b.res,
            b.Cq, b.Cv, b.Cq2, b.qbias2, b.sscale, b.vshift,
            (sbid / b.nbx) * 128, (sbid % b.nbx) * 128);
    } else {
        // REL: 64x64 tile, BK=32, padded LDS carved from As/Bs.
        int lb = bid - a.nwg - b.nwg;           // 512 blocks
        int slb = (lb & 7) * 64 + (lb >> 3);
        int bm = (slb >> 3) * 64, bn = (slb & 7) * 64;
        const int M = NPOS_, N = 512, K = 96;
        unsigned short (*A6)[40] = (unsigned short (*)[40])As;
        unsigned short (*B6)[40] = (unsigned short (*)[40])Bs;
        int wave = tid >> 6, lane = tid & 63;
        f32x4 acc[4] = {};
        int am = tid >> 2, ak = (tid & 3) * 8;
        int bn_ = tid & 63, bk = (tid >> 6) * 8;
        for (int k0 = 0; k0 < K; k0 += 32) {
            s16x8 va = {};
            if (bm + am < M)
                va = *reinterpret_cast<const s16x8*>(
                    (const unsigned short*)relA + (size_t)(bm + am) * K + k0 + ak);
            *reinterpret_cast<s16x8*>(&A6[am][ak]) = va;
            *reinterpret_cast<s16x8*>(&B6[bn_][bk]) =
                *reinterpret_cast<const s16x8*>(
                    (const unsigned short*)relB + (size_t)(bn + bn_) * K + k0 + bk);
            __syncthreads();
            s16x8 af = *reinterpret_cast<const s16x8*>(&A6[wave * 16 + (lane & 15)][(lane >> 4) * 8]);
#pragma unroll
            for (int ns = 0; ns < 4; ns++) {
                s16x8 bf = *reinterpret_cast<const s16x8*>(&B6[ns * 16 + (lane & 15)][(lane >> 4) * 8]);
                acc[ns] = MFMA16(af, bf, acc[ns]);
            }
            __syncthreads();
        }
        int col = lane & 15, rg = (lane >> 4) * 4;
#pragma unroll
        for (int ns = 0; ns < 4; ns++) {
            int n = bn + ns * 16 + col;
#pragma unroll
            for (int r = 0; r < 4; r++) {
                int m = bm + wave * 16 + rg + r;
                if (m < M) relC[(size_t)m * N + n] = f2b(acc[ns][r]);
            }
        }
    }
}

// ---------------------------------------------------------------------------
// Enformer positional features: pos[4095, 96] bf16.
// ---------------------------------------------------------------------------
__global__ __launch_bounds__(64) void pos_kernel(bf16* __restrict__ pos)
{
    int m = blockIdx.x * 64 + threadIdx.x;
    if (m >= NPOS_) return;
    float dist = (float)(m - 2047);
    float ad = fabsf(dist);
    float sgn = (dist > 0.f) ? 1.f : ((dist < 0.f) ? -1.f : 0.f);
    float f[48];
#pragma unroll
    for (int t = 0; t < 16; t++) {
        float hl = exp2f(3.f + (8.f / 15.f) * (float)t);
        f[t] = expf(-0.69314718056f / hl * ad);
    }
#pragma unroll
    for (int t = 0; t < 16; t++) {
        float cw = exp2f((float)(t + 1)) - 1.f;
        f[16 + t] = (cw > ad) ? 1.f : 0.f;
    }
    float pr[16];
    float mx = 0.f;
    if (ad < 0.5f) {
#pragma unroll
        for (int t = 0; t < 16; t++) pr[t] = 1e-8f;
        mx = 1e-8f;
    } else {
        float lad = logf(ad);
#pragma unroll
        for (int t = 0; t < 16; t++) {
            float mean = 128.f * (float)(t + 1);
            float cc = (mean / 64.f) * (mean / 64.f);
            float rate = mean * (1.f / 4096.f);
            float logp = (cc - 1.f) * lad - rate * ad - (lgammaf(cc) - cc * logf(rate));
            float p = expf(logp) + 1e-8f;
            pr[t] = p;
            mx = fmaxf(mx, p);
        }
    }
#pragma unroll
    for (int t = 0; t < 16; t++) f[32 + t] = pr[t] / mx;

    bf16* o = pos + (size_t)m * 96;
#pragma unroll
    for (int c = 0; c < 48; c++) { o[c] = f2b(f[c]); o[48 + c] = f2b(sgn * f[c]); }
}

// ---------------------------------------------------------------------------
// Shifted rel precompute: Tsh[bh][j][i] = dot(kbb[bh,j,:], relq[i-j+511,:]),
// i in [base, base+plen), row pitch plen. Block: 64 j x 256 m super-tile;
// diagonal assembled in LDS (i-space), stored as aligned contiguous chunks.
// ---------------------------------------------------------------------------
#define TP_ 344
__global__ __launch_bounds__(256) void tshift_kernel(
    const bf16* __restrict__ kbb, const bf16* __restrict__ relq,
    bf16* __restrict__ tsh, int base, int plen)
{
    int mc = blockIdx.x, jt = blockIdx.y, bh = blockIdx.z;
    int mbase = mc << 8, jg0 = jt << 6, h = bh & 7;
    int iwin0 = mbase + jg0 - 511 - base;   // global i of (j=jg0, m=mbase)
    if (iwin0 + 318 < 0 || iwin0 >= plen) return;
    int a0 = iwin0 & 7;
    int iwa = iwin0 - a0;                   // aligned global i of LDS col 0
    __shared__ unsigned short Tl[64][TP_];
    int tid = threadIdx.x, wave = tid >> 6, lane = tid & 63;
    int lc = lane & 15, kq = lane >> 4;

    const bf16* ap = kbb + ((size_t)bh * N2_ + jg0 + wave * 16 + lc) * 64 + kq * 8;
    s16x8 af0 = *reinterpret_cast<const s16x8*>(ap);
    s16x8 af1 = *reinterpret_cast<const s16x8*>(ap + 32);

    int jrow = wave * 16 + kq * 4;          // + r = local j row
#pragma unroll
    for (int sub = 0; sub < 2; sub++) {
        int m0 = mbase + sub * 128;
        f32x4 tacc[8] = {};
#pragma unroll
        for (int ns = 0; ns < 8; ns++) {
            const bf16* rp = relq + (size_t)(m0 + ns * 16 + lc) * 512 + h * 64 + kq * 8;
            s16x8 rf0 = *reinterpret_cast<const s16x8*>(rp);
            s16x8 rf1 = *reinterpret_cast<const s16x8*>(rp + 32);
            tacc[ns] = MFMA16(af0, rf0, tacc[ns]);
            tacc[ns] = MFMA16(af1, rf1, tacc[ns]);
        }
#pragma unroll
        for (int ns = 0; ns < 8; ns++)
#pragma unroll
            for (int r = 0; r < 4; r++) {
                int col = sub * 128 + ns * 16 + lc + jrow + r + a0;  // <= 325
                Tl[jrow + r][col] = f2bu(tacc[ns][r]);
            }
    }
    __syncthreads();

    int row = tid >> 2, q = tid & 3;
    int cstart = row + a0;                  // valid cols: [cstart, cstart+256)
    bf16* out = tsh + ((size_t)bh * N2_ + jg0 + row) * (size_t)plen;
#pragma unroll
    for (int s = 0; s < 11; s++) {
        int c = (q + s * 4) * 8;            // 8-elem chunk, 16B aligned
        int i = iwa + c;
        if (c >= cstart && c + 8 <= cstart + 256 && i >= 0 && i + 8 <= plen) {
            *reinterpret_cast<s16x8*>(out + i) =
                *reinterpret_cast<const s16x8*>(&Tl[row][c]);
        } else {
#pragma unroll
            for (int e = 0; e < 8; e++) {
                int ce = c + e, ie = i + e;
                if (ce >= cstart && ce < cstart + 256 && ie >= 0 && ie < plen)
                    out[ie] = *reinterpret_cast<const bf16*>(&Tl[row][ce]);
            }
        }
    }
}

// ---------------------------------------------------------------------------
// MFMA attention pass 1: per 64 q-rows, flash over j. rel term streamed from
// precomputed Tsh (coalesced 64x64 tile stage). Head-major q/k/v.
// ---------------------------------------------------------------------------
__global__ __launch_bounds__(256) void attn1_kernel(
    const bf16* __restrict__ qb, const bf16* __restrict__ kb,
    const bf16* __restrict__ tsh, const bf16* __restrict__ v2,
    bf16* __restrict__ out1, float* __restrict__ mst, float* __restrict__ lst,
    int base, int tpitch)
{
    int bh = blockIdx.y;
    int b = bh >> 3, h = bh & 7;
    int i0 = base + blockIdx.x * 64;
    __shared__ __align__(16) unsigned short Ts[64][72];
    __shared__ __align__(16) unsigned short Ps[64][72];
    __shared__ __align__(16) unsigned short Vs[96][72];
    int tid = threadIdx.x, wave = tid >> 6, lane = tid & 63;
    int lc = lane & 15, kq = lane >> 4;
    int ibase = wave * 16 + kq * 4;

    const bf16* qp = qb + ((size_t)bh * N1_ + i0 + wave * 16 + lc) * 64 + kq * 8;
    s16x8 qf0 = *reinterpret_cast<const s16x8*>(qp);
    s16x8 qf1 = *reinterpret_cast<const s16x8*>(qp + 32);

    int trow = tid >> 2, tchunk = tid & 3;
    const unsigned short* tb0 = (const unsigned short*)tsh
        + ((size_t)bh * N2_ + trow) * tpitch + (i0 - base) + tchunk * 16;
    const unsigned short* vb0 = (const unsigned short*)v2
        + ((size_t)bh * N2_ + trow) * 96 + tchunk * 24;

    float m_run[4], l_run[4];
#pragma unroll
    for (int r = 0; r < 4; r++) { m_run[r] = -1e30f; l_run[r] = 0.f; }
    f32x4 oacc[6] = {};

    for (int j0 = 0; j0 < N2_; j0 += 64) {
        __syncthreads();
        {
            const unsigned short* p = tb0 + (size_t)j0 * tpitch;
            *reinterpret_cast<s16x8*>(&Ts[trow][tchunk * 16]) =
                *reinterpret_cast<const s16x8*>(p);
            *reinterpret_cast<s16x8*>(&Ts[trow][tchunk * 16 + 8]) =
                *reinterpret_cast<const s16x8*>(p + 8);
        }
        {
            const unsigned short* p = vb0 + (size_t)j0 * 96;
            s16x8 w0 = *reinterpret_cast<const s16x8*>(p);
            s16x8 w1 = *reinterpret_cast<const s16x8*>(p + 8);
            s16x8 w2 = *reinterpret_cast<const s16x8*>(p + 16);
            int vd = tchunk * 24;
#pragma unroll
            for (int s = 0; s < 8; s++) Vs[vd + s][trow] = (unsigned short)w0[s];
#pragma unroll
            for (int s = 0; s < 8; s++) Vs[vd + 8 + s][trow] = (unsigned short)w1[s];
#pragma unroll
            for (int s = 0; s < 8; s++) Vs[vd + 16 + s][trow] = (unsigned short)w2[s];
        }
        __syncthreads();

        f32x4 cacc[4] = {};
#pragma unroll
        for (int ns = 0; ns < 4; ns++) {
            const bf16* kp = kb + ((size_t)bh * N2_ + j0 + ns * 16 + lc) * 64 + kq * 8;
            s16x8 kf0 = *reinterpret_cast<const s16x8*>(kp);
            s16x8 kf1 = *reinterpret_cast<const s16x8*>(kp + 32);
            cacc[ns] = MFMA16(qf0, kf0, cacc[ns]);
            cacc[ns] = MFMA16(qf1, kf1, cacc[ns]);
        }
        float Lv[4][4];
#pragma unroll
        for (int ns = 0; ns < 4; ns++) {
            int jloc = ns * 16 + lc;
            s16x4 tv = *reinterpret_cast<const s16x4*>(&Ts[jloc][ibase]);
#pragma unroll
            for (int r = 0; r < 4; r++)
                Lv[ns][r] = cacc[ns][r] + us2f((unsigned short)tv[r]);
        }
#pragma unroll
        for (int r = 0; r < 4; r++) {
            float v = fmaxf(fmaxf(Lv[0][r], Lv[1][r]), fmaxf(Lv[2][r], Lv[3][r]));
            v = fmaxf(v, __shfl_xor(v, 1));
            v = fmaxf(v, __shfl_xor(v, 2));
            v = fmaxf(v, __shfl_xor(v, 4));
            v = fmaxf(v, __shfl_xor(v, 8));
            float mn = fmaxf(m_run[r], v);
            float alpha = __expf(m_run[r] - mn);
            m_run[r] = mn;
            float s = 0.f;
#pragma unroll
            for (int ns = 0; ns < 4; ns++) {
                float p = __expf(Lv[ns][r] - mn);
                Lv[ns][r] = p;
                s += p;
            }
            s += __shfl_xor(s, 1);
            s += __shfl_xor(s, 2);
            s += __shfl_xor(s, 4);
            s += __shfl_xor(s, 8);
            l_run[r] = l_run[r] * alpha + s;
#pragma unroll
            for (int ns6 = 0; ns6 < 6; ns6++) oacc[ns6][r] *= alpha;
        }
#pragma unroll
        for (int ns = 0; ns < 4; ns++)
#pragma unroll
            for (int r = 0; r < 4; r++)
                Ps[ibase + r][ns * 16 + lc] = f2bu(Lv[ns][r]);
#pragma unroll
        for (int kk = 0; kk < 2; kk++) {
            s16x8 pf = *reinterpret_cast<const s16x8*>(&Ps[wave * 16 + lc][kq * 8 + kk * 32]);
#pragma unroll
            for (int ns6 = 0; ns6 < 6; ns6++) {
                s16x8 vf = *reinterpret_cast<const s16x8*>(&Vs[ns6 * 16 + lc][kq * 8 + kk * 32]);
                oacc[ns6] = MFMA16(pf, vf, oacc[ns6]);
            }
        }
    }

    float invl[4];
#pragma unroll
    for (int r = 0; r < 4; r++) invl[r] = 1.f / l_run[r];
#pragma unroll
    for (int ns6 = 0; ns6 < 6; ns6++)
#pragma unroll
        for (int r = 0; r < 4; r++)
            out1[(size_t)(b * N1_ + i0 + ibase + r) * 768 + h * 96 + ns6 * 16 + lc]
                = f2b(oacc[ns6][r] * invl[r]);
    if (lc == 0) {
#pragma unroll
        for (int r = 0; r < 4; r++) {
            mst[(size_t)bh * N1_ + i0 + ibase + r] = m_run[r];
            lst[(size_t)bh * N1_ + i0 + ibase + r] = l_run[r];
        }
    }
}

// ---------------------------------------------------------------------------
// MFMA attention pass 2: per 64 j-rows x 512-i quarter (blockIdx.z), writes
// quarter partials. rel term from Tsh; head-major q/k/v1.
// ---------------------------------------------------------------------------
__global__ __launch_bounds__(256) void attn2_kernel(
    const bf16* __restrict__ qb, const bf16* __restrict__ kb,
    const bf16* __restrict__ tsh, const bf16* __restrict__ v1,
    bf16* __restrict__ out2b, const float* __restrict__ mst,
    const float* __restrict__ lst, int base, int tpitch)
{
    int jt = blockIdx.x, bh = blockIdx.y;
    int b = bh >> 3, h = bh & 7;
    int ib = base + blockIdx.z * 512;
    bf16* out2 = out2b + (size_t)(ib >> 9) * ((size_t)B_ * N2_ * 768);
    int j0 = jt * 64;
    __shared__ __align__(16) unsigned short Ts[64][72];
    __shared__ __align__(16) unsigned short Ps[64][72];
    __shared__ __align__(16) unsigned short Vs[96][72];
    int tid = threadIdx.x, wave = tid >> 6, lane = tid & 63;
    int lc = lane & 15, kq = lane >> 4;
    int ibase = wave * 16 + kq * 4;

    s16x8 kf0[4], kf1[4];
#pragma unroll
    for (int ns = 0; ns < 4; ns++) {
        const bf16* kp = kb + ((size_t)bh * N2_ + j0 + ns * 16 + lc) * 64 + kq * 8;
        kf0[ns] = *reinterpret_cast<const s16x8*>(kp);
        kf1[ns] = *reinterpret_cast<const s16x8*>(kp + 32);
    }

    int trow = tid >> 2, tchunk = tid & 3;
    const unsigned short* tb0 = (const unsigned short*)tsh
        + ((size_t)bh * N2_ + j0 + trow) * tpitch + tchunk * 16;
    const unsigned short* vb0 = (const unsigned short*)v1
        + ((size_t)bh * N1_ + trow) * 96 + tchunk * 24;

    f32x4 oacc[6] = {};
    for (int i0 = ib; i0 < ib + 512; i0 += 64) {
        __syncthreads();
        {
            const unsigned short* p = tb0 + (i0 - base);
            *reinterpret_cast<s16x8*>(&Ts[trow][tchunk * 16]) =
                *reinterpret_cast<const s16x8*>(p);
            *reinterpret_cast<s16x8*>(&Ts[trow][tchunk * 16 + 8]) =
                *reinterpret_cast<const s16x8*>(p + 8);
        }
        {
            const unsigned short* p = vb0 + (size_t)i0 * 96;
            s16x8 w0 = *reinterpret_cast<const s16x8*>(p);
            s16x8 w1 = *reinterpret_cast<const s16x8*>(p + 8);
            s16x8 w2 = *reinterpret_cast<const s16x8*>(p + 16);
            int vd = tchunk * 24;
#pragma unroll
            for (int s = 0; s < 8; s++) Vs[vd + s][trow] = (unsigned short)w0[s];
#pragma unroll
            for (int s = 0; s < 8; s++) Vs[vd + 8 + s][trow] = (unsigned short)w1[s];
#pragma unroll
            for (int s = 0; s < 8; s++) Vs[vd + 16 + s][trow] = (unsigned short)w2[s];
        }
        __syncthreads();

        const bf16* qp = qb + ((size_t)bh * N1_ + i0 + wave * 16 + lc) * 64 + kq * 8;
        s16x8 qf0 = *reinterpret_cast<const s16x8*>(qp);
        s16x8 qf1 = *reinterpret_cast<const s16x8*>(qp + 32);
        f32x4 cacc[4] = {};
#pragma unroll
        for (int ns = 0; ns < 4; ns++) {
            cacc[ns] = MFMA16(qf0, kf0[ns], cacc[ns]);
            cacc[ns] = MFMA16(qf1, kf1[ns], cacc[ns]);
        }
        float mi[4], invli[4];
#pragma unroll
        for (int r = 0; r < 4; r++) {
            mi[r] = mst[(size_t)bh * N1_ + i0 + ibase + r];
            invli[r] = 1.f / lst[(size_t)bh * N1_ + i0 + ibase + r];
        }
#pragma unroll
        for (int ns = 0; ns < 4; ns++) {
            int jloc = ns * 16 + lc;
            s16x4 tv = *reinterpret_cast<const s16x4*>(&Ts[jloc][ibase]);
            s16x4 pw;
#pragma unroll
            for (int r = 0; r < 4; r++) {
                float L = cacc[ns][r] + us2f((unsigned short)tv[r]);
                pw[r] = (short)f2bu(__expf(L - mi[r]) * invli[r]);
            }
            *reinterpret_cast<s16x4*>(&Ps[jloc][ibase]) = pw;
        }
        __syncthreads();
#pragma unroll
        for (int kk = 0; kk < 2; kk++) {
            s16x8 pf = *reinterpret_cast<const s16x8*>(&Ps[wave * 16 + lc][kq * 8 + kk * 32]);
#pragma unroll
            for (int ns6 = 0; ns6 < 6; ns6++) {
                s16x8 vf = *reinterpret_cast<const s16x8*>(&Vs[ns6 * 16 + lc][kq * 8 + kk * 32]);
                oacc[ns6] = MFMA16(pf, vf, oacc[ns6]);
            }
        }
    }

#pragma unroll
    for (int ns6 = 0; ns6 < 6; ns6++)
#pragma unroll
        for (int r = 0; r < 4; r++)
            out2[(size_t)(b * N2_ + j0 + ibase + r) * 768 + h * 96 + ns6 * 16 + lc]
                = f2b(oacc[ns6][r]);
}

// ---------------------------------------------------------------------------
extern "C" void kernel_launch(void* const* d_in, const int* in_sizes, int n_in,
                              void* d_out, int out_size, void* d_ws, size_t ws_size,
                              hipStream_t stream)
{
    (void)in_sizes; (void)n_in; (void)out_size;
    const float* x      = (const float*)d_in[0];
    const float* y0     = (const float*)d_in[1];
    const float* Wres   = (const float*)d_in[2];
    const float* lnx_g  = (const float*)d_in[3];
    const float* lnx_b  = (const float*)d_in[4];
    const float* lny_g  = (const float*)d_in[5];
    const float* lny_b  = (const float*)d_in[6];
    const float* Wq     = (const float*)d_in[7];
    const float* Wk     = (const float*)d_in[8];
    const float* Wv1    = (const float*)d_in[9];
    const float* Wv2    = (const float*)d_in[10];
    const float* Wo1    = (const float*)d_in[11];
    const float* bo1    = (const float*)d_in[12];
    const float* Wo2    = (const float*)d_in[13];
    const float* bo2    = (const float*)d_in[14];
    const float* Wrel   = (const float*)d_in[15];
    const float* rel_pb = (const float*)d_in[16];
    const float* fx_g   = (const float*)d_in[17];
    const float* fx_b   = (const float*)d_in[18];
    const float* fx_w1  = (const float*)d_in[19];
    const float* fx_b1  = (const float*)d_in[20];
    const float* fx_w2  = (const float*)d_in[21];
    const float* fx_b2  = (const float*)d_in[22];
    const float* fy_g   = (const float*)d_in[23];
    const float* fy_b   = (const float*)d_in[24];
    const float* fy_w1  = (const float*)d_in[25];
    const float* fy_b1  = (const float*)d_in[26];
    const float* fy_w2  = (const float*)d_in[27];
    const float* fy_b2  = (const float*)d_in[28];

    float* out_x = (float*)d_out;                          // [4,2048,768] fp32
    float* out_y = out_x + (size_t)B_ * N1_ * D_;          // [4,512,768] fp32
    bf16* out1 = (bf16*)d_out;  // attn out1 parked in d_out (dies before fp32 writes)

    // ---- workspace ----
    char* W = (char*)d_ws;
    size_t o = 0;
    auto alloc = [&](size_t bytes) { char* p = W + o; o += (bytes + 255) & ~(size_t)255; return p; };
    bf16*   qb   = (bf16*)alloc((size_t)B_ * N1_ * 512 * 2);   // head-major [bh][2048][64]; y0b early
    bf16*   kb   = (bf16*)alloc((size_t)B_ * N2_ * 512 * 2);   // [bh][512][64]
    bf16*   posb = (bf16*)alloc((size_t)NPOS_ * 96 * 2);
    bf16*   relq = (bf16*)alloc((size_t)NPOS_ * 512 * 2);
    bf16*   v1b  = (bf16*)alloc((size_t)B_ * N1_ * 768 * 2);   // [bh][2048][96]; Cp slabs early
    bf16*   hx2  = (bf16*)alloc((size_t)B_ * N1_ * 768 * 2);   // out2 quarter slabs / hx / Cp tail
    bf16*   v2b  = (bf16*)alloc((size_t)B_ * N2_ * 768 * 2);   // [bh][512][96]
    float*  yb   = (float*)alloc((size_t)B_ * N2_ * 768 * 4);  // fp32 residual; later hy
    bf16*   kbbb = (bf16*)alloc((size_t)B_ * N2_ * 512 * 2);   // [bh][512][64]
    bf16*   wpool= (bf16*)alloc((size_t)9093120 * 2);          // W^T packed
    float*  mst  = (float*)alloc((size_t)B_ * H_ * N1_ * 4);
    float*  lst  = (float*)alloc((size_t)B_ * H_ * N1_ * 4);

    // Tsh / x1 / y1 time-share the tail region (x1,y1 dead during attention).
    size_t x1y1 = ((size_t)B_ * N1_ * 768 + (size_t)B_ * N2_ * 768) * 2;  // 15.73 MB
    size_t rem = ws_size > o ? ws_size - o : 0;
    int plen = 512;
    if (rem >= (size_t)32 * 512 * 2048 * 2 + 1024) plen = 2048;
    else if (rem >= (size_t)32 * 512 * 1024 * 2 + 1024) plen = 1024;
    size_t tshB = (size_t)32 * 512 * (size_t)plen * 2;
    bf16* tshb = (bf16*)alloc(tshB > x1y1 ? tshB : x1y1);
    bf16* x1 = tshb;
    bf16* y1 = x1 + (size_t)B_ * N1_ * 768;

    bf16* y0b = qb;           // bf16 y0 staging (dead before QV1 writes qb)
    float* Cp = (float*)v1b;  // 4 split-K slabs = v1b+hx2 exactly (25.17 MB)
    bf16* x4 = qb;            // after attention, qb..relq span is dead
    bf16* y4 = v2b;
    bf16* hx = v1b;           // FFNx hidden spans v1b+hx2
    bf16* out2h = hx2;        // 4 quarter slabs (3.15MB each) inside hx2
    bf16* hy = (bf16*)yb;     // FFNy hidden: yb dead after O1|O2 (res read)
    bf16* x4ln = x1;          // Tsh dead by step 7
    bf16* y4ln = y1;

    // packed W^T offsets (elements)
    const unsigned OW_RES = 0, OW_QV1 = 1179648, OW_KV2 = 2162688, OW_O1 = 3145728,
                   OW_O2 = 3735552, OW_REL = 4325376, OW_FXW1 = 4374528,
                   OW_FXW2 = 5554176, OW_FYW1 = 6733824, OW_FYW2 = 7913472;

    PackT pa;
    const float* srcs[12] = {Wres, Wq, Wv1, Wk, Wv2, Wo1, Wo2, Wrel,
                             fx_w1, fx_w2, fy_w1, fy_w2};
    unsigned Ks[12] = {1536, 768, 768, 768, 768, 768, 768, 96, 768, 1536, 768, 1536};
    unsigned Nss[12] = {768, 512, 768, 512, 768, 768, 768, 512, 1536, 768, 1536, 768};
    unsigned dbs[12] = {OW_RES, OW_QV1, OW_QV1 + 393216, OW_KV2, OW_KV2 + 393216,
                        OW_O1, OW_O2, OW_REL, OW_FXW1, OW_FXW2, OW_FYW1, OW_FYW2};
    unsigned drs[12] = {1536, 768, 768, 768, 768, 768, 768, 96, 768, 1536, 768, 1536};
    unsigned cum = 0;
    for (int i = 0; i < 12; i++) {
        pa.src[i] = srcs[i]; pa.K[i] = Ks[i]; pa.N[i] = Nss[i];
        pa.dbase[i] = dbs[i]; pa.drow[i] = drs[i];
        pa.t0[i] = cum;
        cum += (Ks[i] >> 5) * (Nss[i] >> 6);
    }
    pa.t0[12] = cum;

    dim3 blk(256);
    // 0. transpose-pack weights; y0 -> bf16; positional features; LN(x)
    packT_kernel<<<cum, blk, 0, stream>>>(pa, wpool);
    cvt8_kernel<<<(B_ * N2_ * 1536) / 2048, blk, 0, stream>>>(y0, y0b);
    pos_kernel<<<(NPOS_ + 63) / 64, 64, 0, stream>>>(posb);
    lnfull_kernel<float><<<B_ * N1_, 64, 0, stream>>>(x, lnx_g, lnx_b, x1);
    // 1. y = y0 @ W_res: split-K=4 into Cp, then fused reduce + LN(y)
    wres_splitk_kernel<<<384, blk, 0, stream>>>(y0b, wpool + OW_RES, Cp);
    lnred4_kernel<<<B_ * N2_, 64, 0, stream>>>(Cp, lny_g, lny_b, yb, y1);
    // 2. fused projections: QV1 + KV2 + REL in one launch
    {
        GP a{x1, wpool + OW_QV1, nullptr, B_ * N1_, 1280, D_,
             nullptr, 0, nullptr, qb, v1b, nullptr, nullptr, SCALE_, 11, 10, 640};
        GP b{y1, wpool + OW_KV2, nullptr, B_ * N2_, 1280, D_,
             nullptr, 0, nullptr, kb, v2b, kbbb, rel_pb, 1.f, 9, 10, 160};
        dual3_kernel<<<1312, blk, 0, stream>>>(a, b, posb, wpool + OW_REL, relq);
    }
    // 3. shifted-rel precompute + attention, phased to fit workspace
    for (int base = 0; base < N1_; base += plen) {
        tshift_kernel<<<dim3(10, 8, 32), blk, 0, stream>>>(kbbb, relq, tshb, base, plen);
        attn1_kernel<<<dim3(plen / 64, 32), blk, 0, stream>>>(
            qb, kb, tshb, v2b, out1, mst, lst, base, plen);
        attn2_kernel<<<dim3(8, 32, plen / 512), blk, 0, stream>>>(
            qb, kb, tshb, v1b, out2h, mst, lst, base, plen);
    }
    // 4. output projections + residuals: O1 paired with O2 (4-slab sum)
    {
        GP a{out1, wpool + OW_O1, x4, B_ * N1_, D_, D_,
             bo1, 0, x, nullptr, nullptr, nullptr, nullptr, 0.f, 0, 6, 384};
        GP b{out2h, wpool + OW_O2, y4, B_ * N2_, D_, D_,
             bo2, 0, yb, nullptr, nullptr, nullptr, nullptr, 0.f, 0, 6, 96};
        dual128_kernel<0, 2, bf16, float><<<480, blk, 0, stream>>>(a, b);
    }
    // 5. FFN LayerNorms
    lnfull_kernel<bf16><<<B_ * N1_, 64, 0, stream>>>(x4, fx_g, fx_b, x4ln);
    lnfull_kernel<bf16><<<B_ * N2_, 64, 0, stream>>>(y4, fy_g, fy_b, y4ln);
    // 6. FFN W1: FXW1 paired with FYW1 (hy in dead yb region)
    {
        GP a{x4ln, wpool + OW_FXW1, hx, B_ * N1_, 1536, D_,
             fx_b1, 1, nullptr, nullptr, nullptr, nullptr, nullptr, 0.f, 0, 12, 768};
        GP b{y4ln, wpool + OW_FYW1, hy, B_ * N2_, 1536, D_,
             fy_b1, 1, nullptr, nullptr, nullptr, nullptr, nullptr, 0.f, 0, 12, 192};
        dual128_kernel<0, 0, bf16, float><<<960, blk, 0, stream>>>(a, b);
    }
    // 7. FFN W2: FXW2 paired with FYW2 -> fp32 outputs
    {
        GP a{hx, wpool + OW_FXW2, out_x, B_ * N1_, D_, 1536,
             fx_b2, 0, x4, nullptr, nullptr, nullptr, nullptr, 0.f, 0, 6, 384};
        GP b{hy, wpool + OW_FYW2, out_y, B_ * N2_, D_, 1536,
             fy_b2, 0, y4, nullptr, nullptr, nullptr, nullptr, 0.f, 0, 6, 96};
        dual128_kernel<0, 0, float, bf16><<<480, blk, 0, stream>>>(a, b);
    }
}